// Round 5
// baseline (535.535 us; speedup 1.0000x reference)
//
#include <hip/hip_runtime.h>
#include <cstdint>
#include <cstddef>

typedef uint16_t u16;
typedef __bf16 bf16x8 __attribute__((ext_vector_type(8)));
typedef float f32x4 __attribute__((ext_vector_type(4)));
typedef u16 u16x8 __attribute__((ext_vector_type(8)));

// ---- sizes (fixed) ----
// SEQ=2048 HIDDEN=4096 NQ=32 NKV=8 HD=128 WINDOW=1024
// fp32 inputs/output; bf16 MFMA compute with pre-converted bf16 operands.
// qk row layout: [q 4096 | k 1024] stride 5120; V kept transposed (vT).

__device__ __forceinline__ u16 f2bf(float f) {
    union { float f; uint32_t i; } v; v.f = f;
    uint32_t b = v.i;
    return (u16)((b + 0x7FFFu + ((b >> 16) & 1u)) >> 16);  // RNE
}
__device__ __forceinline__ float bf2f(u16 u) {
    union { uint32_t i; float f; } v; v.i = ((uint32_t)u) << 16; return v.f;
}
__device__ __forceinline__ float nanfix(float x, float repl) {
    return (x == x && fabsf(x) < 1e30f) ? x : repl;
}
// async global->LDS, 16B per lane; lds ptr must be wave-uniform base
// (lane i lands at base + i*16) [m97/m104].
__device__ __forceinline__ void async16(const u16* g, u16* l) {
    __builtin_amdgcn_global_load_lds(
        (const __attribute__((address_space(1))) uint32_t*)g,
        (__attribute__((address_space(3))) uint32_t*)l, 16, 0, 0);
}

template<int N> __device__ __forceinline__ void waitvm() {
    static_assert(N >= 0 && N <= 14, "vmcnt range");
    if constexpr (N == 0)  asm volatile("s_waitcnt vmcnt(0)" ::: "memory");
    else if constexpr (N == 1)  asm volatile("s_waitcnt vmcnt(1)" ::: "memory");
    else if constexpr (N == 2)  asm volatile("s_waitcnt vmcnt(2)" ::: "memory");
    else if constexpr (N == 3)  asm volatile("s_waitcnt vmcnt(3)" ::: "memory");
    else if constexpr (N == 4)  asm volatile("s_waitcnt vmcnt(4)" ::: "memory");
    else if constexpr (N == 5)  asm volatile("s_waitcnt vmcnt(5)" ::: "memory");
    else if constexpr (N == 6)  asm volatile("s_waitcnt vmcnt(6)" ::: "memory");
    else if constexpr (N == 7)  asm volatile("s_waitcnt vmcnt(7)" ::: "memory");
    else if constexpr (N == 8)  asm volatile("s_waitcnt vmcnt(8)" ::: "memory");
    else if constexpr (N == 9)  asm volatile("s_waitcnt vmcnt(9)" ::: "memory");
    else if constexpr (N == 10) asm volatile("s_waitcnt vmcnt(10)" ::: "memory");
    else if constexpr (N == 11) asm volatile("s_waitcnt vmcnt(11)" ::: "memory");
    else if constexpr (N == 12) asm volatile("s_waitcnt vmcnt(12)" ::: "memory");
    else if constexpr (N == 13) asm volatile("s_waitcnt vmcnt(13)" ::: "memory");
    else                        asm volatile("s_waitcnt vmcnt(14)" ::: "memory");
}

// ---------------- fp32 -> bf16 flat convert (n multiple of 2048*8) -----------
__global__ void cvt_k(const float* __restrict__ in, u16* __restrict__ out) {
    const size_t i = ((size_t)blockIdx.x * 256 + threadIdx.x) * 8;
    const f32x4 a = *(const f32x4*)&in[i], b = *(const f32x4*)&in[i + 4];
    u16x8 s;
    #pragma unroll
    for (int e = 0; e < 4; e++) { s[e] = f2bf(a[e]); s[4 + e] = f2bf(b[e]); }
    *(u16x8*)&out[i] = s;
}

// ---------- fp32 (R,C) -> bf16 (C,R) transpose+convert, 32x32 tiles ----------
__global__ void cvtT_k(const float* __restrict__ in, u16* __restrict__ out,
                       int R, int C) {
    __shared__ float tile[32][33];
    const int bx = blockIdx.x * 32, by = blockIdx.y * 32;
    const int tx = threadIdx.x, ty = threadIdx.y;   // (32,8)
    #pragma unroll
    for (int i = 0; i < 32; i += 8)
        tile[ty + i][tx] = in[(size_t)(by + ty + i) * C + (bx + tx)];
    __syncthreads();
    #pragma unroll
    for (int i = 0; i < 32; i += 8)
        out[(size_t)(bx + ty + i) * R + (by + tx)] = f2bf(tile[tx][ty + i]);
}

// =====================================================================
// 256 x (64*NF) / BK=64 / 8-wave (2Mx4N) GEMM.
// Skeleton per phase (proven R4): {ds_read frags ; issue stage loads}
//   -> s_barrier -> lgkmcnt(0)+sched_barrier(0) -> setprio(1) MFMA setprio(0)
//   -> counted waitvm -> s_barrier.
// NEW (R5): group-ring staging, 6-phase lookahead with the same 2 buffers.
// A-group g of tile t is last read at phase g; B(t) only at ph0. So:
//   ph0: issue A3(t+1) -> other-parity A buf
//   ph1: issue B(t+2)+A0(t+2) -> SAME-parity bufs (their last readers done)
//   ph2: issue A1(t+2)      ph3: issue A2(t+2)
// Every issue sits one PHASE_END barrier after its slot's last reader (WAR
// safe); every wait targets a load issued exactly 6 phases earlier.
// Queue-simulated waits (end of phase, before 2nd barrier):
//   steady (ISS=2): {NF+6, 2NF+7, 2NF+6, NF+6}
//   tile 62 (ISS=1, A3(63) only): {NF+6, NF+5, NF+4, 3}
//   tile 63 (ISS=0): {2, 1, 0, -}
// Prologue stages [B(0),A0..A3(0), B(1),A0..A2(1)] then waitvm<NF+6>.
// LDS swizzle: LDS[r][c]=global[r][c^(r&7)] via pre-swizzled global source
// (global_load_lds dest lane-linear) + swizzled ds_read (rule #21).
// =====================================================================

#define SB(g, kk, dst) async16(Bb + (size_t)((g) * 64 + rg) * 4096 + (kk) + sc, \
                               (dst) + ((g) * 64 + wave * 8) * 64)
#define SA(g, kk, dst) async16(Ab + (size_t)((g) * 32 + aro) * 4096 + (kk) + sc, \
                               (dst) + ((g) * 32 + wbA) * 64)

#define LOADA(P) do {                                                           \
    const int r0_ = wr * 128 + (2 * (P)) * 16 + lr;                             \
    const int r1_ = r0_ + 16;                                                   \
    _Pragma("unroll")                                                           \
    for (int ks = 0; ks < 2; ks++) {                                            \
        a0[ks] = *(const bf16x8*)&Ac[r0_ * 64 + (((ks * 4 + qd) ^ (r0_ & 7)) * 8)]; \
        a1[ks] = *(const bf16x8*)&Ac[r1_ * 64 + (((ks * 4 + qd) ^ (r1_ & 7)) * 8)]; \
    }                                                                           \
} while (0)

#define MFMAP(P) do {                                                           \
    __builtin_amdgcn_s_setprio(1);                                              \
    _Pragma("unroll")                                                           \
    for (int nn = 0; nn < NF; nn++)                                             \
        _Pragma("unroll")                                                       \
        for (int ks = 0; ks < 2; ks++) {                                        \
            acc[2 * (P)][nn]     = __builtin_amdgcn_mfma_f32_16x16x32_bf16(     \
                a0[ks], b[nn][ks], acc[2 * (P)][nn], 0, 0, 0);                  \
            acc[2 * (P) + 1][nn] = __builtin_amdgcn_mfma_f32_16x16x32_bf16(     \
                a1[ks], b[nn][ks], acc[2 * (P) + 1][nn], 0, 0, 0);              \
        }                                                                       \
    __builtin_amdgcn_s_setprio(0);                                              \
} while (0)

#define PHASE_SYNC() do {                                                       \
    __builtin_amdgcn_s_barrier();                                               \
    asm volatile("s_waitcnt lgkmcnt(0)" ::: "memory");                          \
    __builtin_amdgcn_sched_barrier(0);                                          \
} while (0)

#define PHASE_END() do {                                                        \
    __builtin_amdgcn_s_barrier();                                               \
    __builtin_amdgcn_sched_barrier(0);                                          \
} while (0)

// ISS: 2 = steady (stage A3(t+1) + tile t+2); 1 = tile 62 (A3(63) only);
//      0 = tile 63 (drain).
template<int NF, int ISS>
__device__ __forceinline__ void tile_body(
    const u16* __restrict__ Ab, const u16* __restrict__ Bb,
    u16* Ac, u16* Bc, u16* Aoth, int k1, int k2,
    int wave, int lr, int qd, int wr, int wc,
    int rg, int sc, int aro, int wbA, f32x4 (&acc)[8][NF])
{
    constexpr int W0 = (ISS == 0) ? 2 : NF + 6;
    constexpr int W1 = (ISS == 2) ? 2 * NF + 7 : (ISS == 1 ? NF + 5 : 1);
    constexpr int W2 = (ISS == 2) ? 2 * NF + 6 : (ISS == 1 ? NF + 4 : 0);

    bf16x8 b[NF][2];
    bf16x8 a0[2], a1[2];

    // ---------- phase 0: read B(all)+A{0,1}; issue A3(t+1) ----------
    #pragma unroll
    for (int nn = 0; nn < NF; nn++)
        #pragma unroll
        for (int ks = 0; ks < 2; ks++) {
            const int row = wc * (16 * NF) + nn * 16 + lr;
            b[nn][ks] = *(const bf16x8*)&Bc[row * 64 + (((ks * 4 + qd) ^ (row & 7)) * 8)];
        }
    LOADA(0);
    if constexpr (ISS >= 1) SA(3, k1, Aoth);
    PHASE_SYNC();
    MFMAP(0);
    waitvm<W0>();
    PHASE_END();
    // ---------- phase 1: read A{2,3}; issue B(t+2),A0(t+2) ----------
    LOADA(1);
    if constexpr (ISS == 2) {
        #pragma unroll
        for (int g = 0; g < NF; g++) SB(g, k2, Bc);
        SA(0, k2, Ac);
    }
    PHASE_SYNC();
    MFMAP(1);
    waitvm<W1>();
    PHASE_END();
    // ---------- phase 2: read A{4,5}; issue A1(t+2) ----------
    LOADA(2);
    if constexpr (ISS == 2) SA(1, k2, Ac);
    PHASE_SYNC();
    MFMAP(2);
    waitvm<W2>();
    PHASE_END();
    // ---------- phase 3: read A{6,7}; issue A2(t+2) ----------
    LOADA(3);
    if constexpr (ISS == 2) SA(2, k2, Ac);
    PHASE_SYNC();
    MFMAP(3);
    if constexpr (ISS == 2) waitvm<NF + 6>();
    else if constexpr (ISS == 1) waitvm<3>();
    PHASE_END();
}

// MODE 0: qkv epilogue (bf16 split store qk/vT), NF=3. MODE 1: f32 store, NF=2.
// Grid: 8 m-tiles x 32 n-tiles = 256 blocks. XCD patch: 2 m-groups x 4
// n-groups of XCDs; each XCD owns a 4m x 8n tile patch (min L2 fill).
template<int NF, int MODE>
__global__ __launch_bounds__(512, 2) void gemm256(
    const u16* __restrict__ A, const u16* __restrict__ BT,
    u16* __restrict__ qk, u16* __restrict__ vT, float* __restrict__ Cf)
{
    alignas(16) __shared__ u16 As[2][256 * 64];
    alignas(16) __shared__ u16 Bs[2][NF * 64 * 64];

    const int tid = threadIdx.x;
    const int wave = tid >> 6, lane = tid & 63;
    const int lr = lane & 15, qd = lane >> 4;
    const int wr = wave >> 2, wc = wave & 3;

    // XCD patch swizzle (bijective over 256 blocks)
    const int x = blockIdx.x & 7, bi = blockIdx.x >> 3;   // xcd, idx in [0,32)
    const int m0 = ((x & 1) * 4 + (bi & 3)) * 256;
    const int n0 = ((x >> 1) * 8 + (bi >> 2)) * (NF * 64);

    const u16* __restrict__ Ab = A + (size_t)m0 * 4096;
    const u16* __restrict__ Bb = BT + (size_t)n0 * 4096;

    // staging coords
    const int rg = tid >> 3;                        // 0..63
    const int sc = ((tid & 7) ^ (rg & 7)) * 8;      // pre-swizzled chunk (u16)
    const int aro = (rg < 32) ? rg : (96 + rg);     // interleaved A-group row
    const int wbA = (wave < 4) ? wave * 8 : (96 + wave * 8);

    f32x4 acc[8][NF];
    #pragma unroll
    for (int i = 0; i < 8; i++)
        #pragma unroll
        for (int j = 0; j < NF; j++) acc[i][j] = (f32x4){0.f, 0.f, 0.f, 0.f};

    // prologue: stage tile 0 fully + tile 1 minus A3, in steady queue order
    #pragma unroll
    for (int g = 0; g < NF; g++) SB(g, 0, &Bs[0][0]);
    SA(0, 0, &As[0][0]); SA(1, 0, &As[0][0]); SA(2, 0, &As[0][0]); SA(3, 0, &As[0][0]);
    #pragma unroll
    for (int g = 0; g < NF; g++) SB(g, 64, &Bs[1][0]);
    SA(0, 64, &As[1][0]); SA(1, 64, &As[1][0]); SA(2, 64, &As[1][0]);
    waitvm<NF + 6>();                 // B(0),A0(0) landed
    __builtin_amdgcn_s_barrier();
    __builtin_amdgcn_sched_barrier(0);

    // tiles 0..61 steady (pairs), 62 = A3-only, 63 = drain. (K=4096, BK=64)
    for (int t = 0; t < 62; t += 2) {
        tile_body<NF, 2>(Ab, Bb, &As[0][0], &Bs[0][0], &As[1][0],
                         (t + 1) * 64, (t + 2) * 64,
                         wave, lr, qd, wr, wc, rg, sc, aro, wbA, acc);
        tile_body<NF, 2>(Ab, Bb, &As[1][0], &Bs[1][0], &As[0][0],
                         (t + 2) * 64, (t + 3) * 64,
                         wave, lr, qd, wr, wc, rg, sc, aro, wbA, acc);
    }
    tile_body<NF, 1>(Ab, Bb, &As[0][0], &Bs[0][0], &As[1][0], 63 * 64, 0,
                     wave, lr, qd, wr, wc, rg, sc, aro, wbA, acc);   // t = 62
    tile_body<NF, 0>(Ab, Bb, &As[1][0], &Bs[1][0], &As[0][0], 0, 0,
                     wave, lr, qd, wr, wc, rg, sc, aro, wbA, acc);   // t = 63

    // epilogue: C/D layout col=lane&15, row=(lane>>4)*4+reg [m89/m91]
    #pragma unroll
    for (int i = 0; i < 8; i++)
        #pragma unroll
        for (int j = 0; j < NF; j++) {
            const int col = n0 + wc * (16 * NF) + j * 16 + lr;
            #pragma unroll
            for (int r = 0; r < 4; r++) {
                const int row = m0 + wr * 128 + i * 16 + qd * 4 + r;
                if constexpr (MODE == 0) {
                    const u16 val = f2bf(nanfix(acc[i][j][r], 1000.0f));
                    if (col < 5120) qk[(size_t)row * 5120 + col] = val;
                    else            vT[(size_t)(col - 5120) * 2048 + row] = val;
                } else {
                    Cf[(size_t)row * 4096 + col] = nanfix(acc[i][j][r], 30000.0f);
                }
            }
        }
}

#undef SB
#undef SA
#undef LOADA
#undef MFMAP
#undef PHASE_SYNC
#undef PHASE_END

// ---------------- NeoX RoPE in-place on qk (stride 5120) ----------------------
// 256 threads = 4 heads per block; grid (2048, 10).
__global__ void rope_k(u16* __restrict__ qk, const int* __restrict__ positions) {
    const int s = blockIdx.x;
    const int h = blockIdx.y * 4 + (threadIdx.x >> 6);  // 0..39
    const int t = threadIdx.x & 63;                      // pair index
    u16* base = qk + (size_t)s * 5120 + ((h < 32) ? h * 128 : 4096 + (h - 32) * 128);
    const float pos = (float)positions[s];
    const float freq = pos * exp2f(-(float)t * (19.931568569324174f / 64.f));
    const float c = cosf(freq), sn = sinf(freq);
    const float x1 = bf2f(base[t]), x2 = bf2f(base[t + 64]);
    base[t]      = f2bf(x1 * c - x2 * sn);
    base[t + 64] = f2bf(x2 * c + x1 * sn);
}

// ---------------- flash attention, window=1024, sink, GQA 4:1 ------------------
// grid (q-tile 32, head 32), 256 threads = 4 waves; wave owns 16 q-rows.
// K staged async w/ XOR chunk swizzle; V from vT w/ stride-72 LDS; Q direct.
__global__ __launch_bounds__(256) void attn_k(
    const u16* __restrict__ qk, const u16* __restrict__ vT,
    const float* __restrict__ sink, u16* __restrict__ out)
{
    alignas(16) __shared__ u16 Ks[64 * 128];    // slot = row*16 + (chunk ^ (row&15))
    alignas(16) __shared__ u16 VsT[128 * 72];   // [vd][seq], stride 72 (144B = 9x16B)
    alignas(16) __shared__ u16 Ps[4][16 * 72];

    const int h = blockIdx.y, hk = h >> 2;
    const int q0 = blockIdx.x * 64;
    const int tid = threadIdx.x, wave = tid >> 6, lane = tid & 63;
    const int lr = lane & 15, qd = lane >> 4;
    const float scaling = 0.08838834764831845f;  // 1/sqrt(128)

    // Q fragments straight from global (post-RoPE)
    bf16x8 aq[4];
    #pragma unroll
    for (int kc = 0; kc < 4; kc++)
        aq[kc] = *(const bf16x8*)&qk[(size_t)(q0 + wave * 16 + lr) * 5120 + h * 128 + kc * 32 + qd * 8];

    const float sinkv = sink[h];
    float m_run[4], l_run[4];
    #pragma unroll
    for (int r = 0; r < 4; r++) { m_run[r] = sinkv; l_run[r] = 0.f; }
    f32x4 acc_o[8];
    #pragma unroll
    for (int i = 0; i < 8; i++) acc_o[i] = (f32x4){0.f, 0.f, 0.f, 0.f};

    const int jlo = (q0 - 1023) > 0 ? (q0 - 1023) : 0;
    const int t0 = jlo >> 6, t1 = q0 >> 6;

    for (int kt = t0; kt <= t1; kt++) {
        const int j0 = kt * 64;
        __syncthreads();  // WAR: prior-iter Ks/VsT/Ps reads complete
        // K tile: 64 rows x 128 u16 = 1024 chunks of 16B, async, XOR-swizzled
        #pragma unroll
        for (int p = 0; p < 4; p++) {
            const int idx = p * 256 + tid;
            const int r = idx >> 4, cs = idx & 15, c = cs ^ (r & 15);
            async16(&qk[(size_t)(j0 + r) * 5120 + 4096 + hk * 128 + c * 8],
                    Ks + (p * 256 + wave * 64) * 8);
        }
        // V tile from vT: 128 vd-rows x 64 seq
        #pragma unroll
        for (int p = 0; p < 4; p++) {
            const int idx = p * 256 + tid;
            const int vd = idx >> 3, sc2 = (idx & 7) * 8;
            const u16x8 v = *(const u16x8*)&vT[(size_t)(hk * 128 + vd) * 2048 + j0 + sc2];
            *(u16x8*)&VsT[vd * 72 + sc2] = v;
        }
        __syncthreads();

        // S = Q K^T : per-wave 16x64
        float sv[4][4];
        #pragma unroll
        for (int nt = 0; nt < 4; nt++) {
            f32x4 s = (f32x4){0.f, 0.f, 0.f, 0.f};
            #pragma unroll
            for (int kc = 0; kc < 4; kc++) {
                const int krow = nt * 16 + lr;
                const bf16x8 bk = *(const bf16x8*)&Ks[(krow * 16 + ((kc * 4 + qd) ^ lr)) * 8];
                s = __builtin_amdgcn_mfma_f32_16x16x32_bf16(aq[kc], bk, s, 0, 0, 0);
            }
            #pragma unroll
            for (int r = 0; r < 4; r++) sv[nt][r] = s[r];
        }

        // mask + scale + rowmax (row = qd*4+r, col = nt*16+lr)
        float rmax[4] = {-1e30f, -1e30f, -1e30f, -1e30f};
        #pragma unroll
        for (int nt = 0; nt < 4; nt++) {
            const int kpos = j0 + nt * 16 + lr;
            #pragma unroll
            for (int r = 0; r < 4; r++) {
                const int qpos = q0 + wave * 16 + qd * 4 + r;
                const bool ok = (kpos <= qpos) && (qpos - kpos < 1024);
                const float x = ok ? sv[nt][r] * scaling : -1e30f;
                sv[nt][r] = x;
                rmax[r] = fmaxf(rmax[r], x);
            }
        }
        #pragma unroll
        for (int off = 1; off < 16; off <<= 1)
            #pragma unroll
            for (int r = 0; r < 4; r++)
                rmax[r] = fmaxf(rmax[r], __shfl_xor(rmax[r], off, 64));

        float alpha[4], rsum[4];
        #pragma unroll
        for (int r = 0; r < 4; r++) {
            const float mnew = fmaxf(m_run[r], rmax[r]);
            alpha[r] = __expf(m_run[r] - mnew);
            m_run[r] = mnew;
            rsum[r] = 0.f;
        }
        #pragma unroll
        for (int nt = 0; nt < 4; nt++)
            #pragma unroll
            for (int r = 0; r < 4; r++) {
                const float p = __expf(sv[nt][r] - m_run[r]);
                sv[nt][r] = p;
                rsum[r] += p;
            }
        #pragma unroll
        for (int off = 1; off < 16; off <<= 1)
            #pragma unroll
            for (int r = 0; r < 4; r++)
                rsum[r] += __shfl_xor(rsum[r], off, 64);
        #pragma unroll
        for (int r = 0; r < 4; r++)
            l_run[r] = l_run[r] * alpha[r] + rsum[r];

        // P (C-layout) -> LDS bridge (stride 72); barrier before A-layout read
        #pragma unroll
        for (int nt = 0; nt < 4; nt++)
            #pragma unroll
            for (int r = 0; r < 4; r++)
                Ps[wave][(qd * 4 + r) * 72 + nt * 16 + lr] = f2bf(sv[nt][r]);

        #pragma unroll
        for (int i = 0; i < 8; i++)
            #pragma unroll
            for (int r = 0; r < 4; r++) acc_o[i][r] *= alpha[r];

        __syncthreads();

        bf16x8 pa[2];
        #pragma unroll
        for (int kc = 0; kc < 2; kc++)
            pa[kc] = *(const bf16x8*)&Ps[wave][lr * 72 + kc * 32 + qd * 8];

        #pragma unroll
        for (int nt = 0; nt < 8; nt++)
            #pragma unroll
            for (int kc = 0; kc < 2; kc++) {
                const bf16x8 bv = *(const bf16x8*)&VsT[(nt * 16 + lr) * 72 + kc * 32 + qd * 8];
                acc_o[nt] = __builtin_amdgcn_mfma_f32_16x16x32_bf16(pa[kc], bv, acc_o[nt], 0, 0, 0);
            }
    }

    float invd[4];
    #pragma unroll
    for (int r = 0; r < 4; r++)
        invd[r] = 1.f / (l_run[r] + __expf(sinkv - m_run[r]));
    #pragma unroll
    for (int nt = 0; nt < 8; nt++) {
        const int col = h * 128 + nt * 16 + lr;
        #pragma unroll
        for (int r = 0; r < 4; r++) {
            const int row = q0 + wave * 16 + qd * 4 + r;
            out[(size_t)row * 4096 + col] = f2bf(nanfix(acc_o[nt][r] * invd[r], 8.0f));
        }
    }
}

extern "C" void kernel_launch(void* const* d_in, const int* in_sizes, int n_in,
                              void* d_out, int out_size, void* d_ws, size_t ws_size,
                              hipStream_t stream)
{
    (void)in_sizes; (void)n_in; (void)out_size; (void)ws_size;
    const float* hidden    = (const float*)d_in[0];
    const int*   positions = (const int*)d_in[1];
    const float* wq   = (const float*)d_in[2];
    const float* wk   = (const float*)d_in[3];
    const float* wv   = (const float*)d_in[4];
    const float* wo   = (const float*)d_in[5];
    const float* sink = (const float*)d_in[6];
    float* out = (float*)d_out;

    // Workspace (88 MB peak):
    //  [0,16M)   hiddenB (2048x4096 bf16)      -- dead after gemm_qkv
    //  [16,64M)  wqkvT (6144x4096 bf16)        -- dead after gemm_qkv
    //  [64,84M)  qk (2048x5120 bf16)
    //  [84,88M)  vT (1024x2048 bf16)
    //  reuse:    [0,32M) woT (4096x4096 bf16), [32,48M) attnB (2048x4096 bf16)
    char* ws = (char*)d_ws;
    u16* hiddenB = (u16*)(ws);
    u16* wqkvT   = (u16*)(ws + (size_t)16777216);
    u16* qk      = (u16*)(ws + (size_t)67108864);
    u16* vT      = (u16*)(ws + (size_t)88080384);
    u16* woT     = (u16*)(ws);
    u16* attnB   = (u16*)(ws + (size_t)33554432);

    // convert / transpose to bf16 (bandwidth passes)
    cvt_k <<<4096, 256, 0, stream>>>(hidden, hiddenB);
    cvtT_k<<<dim3(128, 128), dim3(32, 8), 0, stream>>>(wq, wqkvT, 4096, 4096);
    cvtT_k<<<dim3(32, 128),  dim3(32, 8), 0, stream>>>(wk, wqkvT + (size_t)4096 * 4096, 4096, 1024);
    cvtT_k<<<dim3(32, 128),  dim3(32, 8), 0, stream>>>(wv, wqkvT + (size_t)5120 * 4096, 4096, 1024);

    // fused QKV projection (q,k -> qk; v -> vT): 2048x6144, tiles 256x192,
    // grid 8x32 = 256 blocks (exact CU fill)
    gemm256<3, 0><<<256, 512, 0, stream>>>(hiddenB, wqkvT, qk, vT, nullptr);

    // wqkvT/hiddenB dead -> wo transpose into their space
    cvtT_k<<<dim3(128, 128), dim3(32, 8), 0, stream>>>(wo, woT, 4096, 4096);

    rope_k<<<dim3(2048, 10), 256, 0, stream>>>(qk, positions);
    attn_k<<<dim3(32, 32), 256, 0, stream>>>(qk, vT, sink, attnB);

    // out GEMM: 2048x4096, tiles 256x128, grid 8x32 = 256 blocks
    gemm256<2, 1><<<256, 512, 0, stream>>>(attnB, woT, nullptr, nullptr, out);
}

// Round 6
// 518.128 us; speedup vs baseline: 1.0336x; 1.0336x over previous
//
#include <hip/hip_runtime.h>
#include <cstdint>
#include <cstddef>

typedef uint16_t u16;
typedef __bf16 bf16x8 __attribute__((ext_vector_type(8)));
typedef float f32x4 __attribute__((ext_vector_type(4)));
typedef u16 u16x8 __attribute__((ext_vector_type(8)));

// ---- sizes (fixed) ----
// SEQ=2048 HIDDEN=4096 NQ=32 NKV=8 HD=128 WINDOW=1024
// fp32 inputs/output; bf16 MFMA compute with pre-converted bf16 operands.
// qk row layout: [q 4096 | k 1024] stride 5120; V kept transposed (vT).

__device__ __forceinline__ u16 f2bf(float f) {
    union { float f; uint32_t i; } v; v.f = f;
    uint32_t b = v.i;
    return (u16)((b + 0x7FFFu + ((b >> 16) & 1u)) >> 16);  // RNE
}
__device__ __forceinline__ float bf2f(u16 u) {
    union { uint32_t i; float f; } v; v.i = ((uint32_t)u) << 16; return v.f;
}
__device__ __forceinline__ float nanfix(float x, float repl) {
    return (x == x && fabsf(x) < 1e30f) ? x : repl;
}
// async global->LDS, 16B per lane; lds ptr must be wave-uniform base
// (lane i lands at base + i*16) [m97/m104].
__device__ __forceinline__ void async16(const u16* g, u16* l) {
    __builtin_amdgcn_global_load_lds(
        (const __attribute__((address_space(1))) uint32_t*)g,
        (__attribute__((address_space(3))) uint32_t*)l, 16, 0, 0);
}

template<int N> __device__ __forceinline__ void waitvm() {
    static_assert(N >= 0 && N <= 14, "vmcnt range");
    if constexpr (N == 0)  asm volatile("s_waitcnt vmcnt(0)" ::: "memory");
    else if constexpr (N == 1)  asm volatile("s_waitcnt vmcnt(1)" ::: "memory");
    else if constexpr (N == 2)  asm volatile("s_waitcnt vmcnt(2)" ::: "memory");
    else if constexpr (N == 3)  asm volatile("s_waitcnt vmcnt(3)" ::: "memory");
    else if constexpr (N == 4)  asm volatile("s_waitcnt vmcnt(4)" ::: "memory");
    else if constexpr (N == 5)  asm volatile("s_waitcnt vmcnt(5)" ::: "memory");
    else if constexpr (N == 6)  asm volatile("s_waitcnt vmcnt(6)" ::: "memory");
    else if constexpr (N == 7)  asm volatile("s_waitcnt vmcnt(7)" ::: "memory");
    else if constexpr (N == 8)  asm volatile("s_waitcnt vmcnt(8)" ::: "memory");
    else if constexpr (N == 9)  asm volatile("s_waitcnt vmcnt(9)" ::: "memory");
    else if constexpr (N == 10) asm volatile("s_waitcnt vmcnt(10)" ::: "memory");
    else if constexpr (N == 11) asm volatile("s_waitcnt vmcnt(11)" ::: "memory");
    else if constexpr (N == 12) asm volatile("s_waitcnt vmcnt(12)" ::: "memory");
    else if constexpr (N == 13) asm volatile("s_waitcnt vmcnt(13)" ::: "memory");
    else                        asm volatile("s_waitcnt vmcnt(14)" ::: "memory");
}

// ---------------- fp32 -> bf16 flat convert (n multiple of 2048*8) -----------
__global__ void cvt_k(const float* __restrict__ in, u16* __restrict__ out) {
    const size_t i = ((size_t)blockIdx.x * 256 + threadIdx.x) * 8;
    const f32x4 a = *(const f32x4*)&in[i], b = *(const f32x4*)&in[i + 4];
    u16x8 s;
    #pragma unroll
    for (int e = 0; e < 4; e++) { s[e] = f2bf(a[e]); s[4 + e] = f2bf(b[e]); }
    *(u16x8*)&out[i] = s;
}

// ---------- fp32 (R,C) -> bf16 (C,R) transpose+convert, 32x32 tiles ----------
__global__ void cvtT_k(const float* __restrict__ in, u16* __restrict__ out,
                       int R, int C) {
    __shared__ float tile[32][33];
    const int bx = blockIdx.x * 32, by = blockIdx.y * 32;
    const int tx = threadIdx.x, ty = threadIdx.y;   // (32,8)
    #pragma unroll
    for (int i = 0; i < 32; i += 8)
        tile[ty + i][tx] = in[(size_t)(by + ty + i) * C + (bx + tx)];
    __syncthreads();
    #pragma unroll
    for (int i = 0; i < 32; i += 8)
        out[(size_t)(bx + ty + i) * R + (by + tx)] = f2bf(tile[tx][ty + i]);
}

// =====================================================================
// 256 x (64*NF) / BK=64 / 8-wave (2Mx4N) GEMM.
// R6: TWO phases per K-tile (was 4). Phase P reads A-frags P*4..P*4+3
// (+ all B in ph0) and runs 4*NF*2 MFMAs. Barriers/tile: 8 -> 4; MFMA
// cluster 2x bigger so the ~700cyc fixed phase overhead (ds_read chain +
// barriers + lgkm drain) is amortized over 2x the MFMA work.
// Staging: ALL of tile t+1 (group of NF+4 loads: B0..B(NF-1),A0..A3)
// issued at tile t ph0 into the other-parity buffer (WAR safe: that
// buffer's last readers drained at the t-1 tile-boundary barrier).
// Per-wave queue-sim waits (before 2nd barrier of each phase):
//   steady ph0: NF+4  (retires A2,A3(t); leaves t+1's group)
//   steady ph1: 2     (retires B..A1(t+1); leaves A2,A3(t+1))
//   drain tile ph0: 0 ; ph1: none.  Prologue: stage tile0, waitvm<2>.
// A-group g covers frag-rows {2g,2g+1} of BOTH wr halves (aro mapping),
// so ph0 needs loads 1..NF+2 and ph1 needs the last 2 -- matches waits.
// LDS swizzle: LDS[r][c]=global[r][c^(r&7)] via pre-swizzled global source
// (global_load_lds dest lane-linear) + swizzled ds_read (rule #21).
// =====================================================================

#define SB(g, kk, dst) async16(Bb + (size_t)((g) * 64 + rg) * 4096 + (kk) + sc, \
                               (dst) + ((g) * 64 + wave * 8) * 64)
#define SA(g, kk, dst) async16(Ab + (size_t)((g) * 32 + aro) * 4096 + (kk) + sc, \
                               (dst) + ((g) * 32 + wbA) * 64)

#define LOADA4(PH) do {                                                         \
    _Pragma("unroll")                                                           \
    for (int f = 0; f < 4; f++) {                                               \
        const int row = wr * 128 + ((PH) * 4 + f) * 16 + lr;                    \
        _Pragma("unroll")                                                       \
        for (int ks = 0; ks < 2; ks++)                                          \
            a[f][ks] = *(const bf16x8*)&Ac[row * 64 + (((ks * 4 + qd) ^ (row & 7)) * 8)]; \
    }                                                                           \
} while (0)

#define MFMAP4(PH) do {                                                         \
    __builtin_amdgcn_s_setprio(1);                                              \
    _Pragma("unroll")                                                           \
    for (int f = 0; f < 4; f++)                                                 \
        _Pragma("unroll")                                                       \
        for (int nn = 0; nn < NF; nn++)                                         \
            _Pragma("unroll")                                                   \
            for (int ks = 0; ks < 2; ks++)                                      \
                acc[(PH) * 4 + f][nn] = __builtin_amdgcn_mfma_f32_16x16x32_bf16(\
                    a[f][ks], b[nn][ks], acc[(PH) * 4 + f][nn], 0, 0, 0);       \
    __builtin_amdgcn_s_setprio(0);                                              \
} while (0)

#define PHASE_SYNC() do {                                                       \
    __builtin_amdgcn_s_barrier();                                               \
    asm volatile("s_waitcnt lgkmcnt(0)" ::: "memory");                          \
    __builtin_amdgcn_sched_barrier(0);                                          \
} while (0)

#define PHASE_END() do {                                                        \
    __builtin_amdgcn_s_barrier();                                               \
    __builtin_amdgcn_sched_barrier(0);                                          \
} while (0)

// ISS: 1 = stage tile t+1 (k1) into An/Bn at ph0; 0 = last tile (drain).
template<int NF, int ISS>
__device__ __forceinline__ void tile_body(
    const u16* __restrict__ Ab, const u16* __restrict__ Bb,
    const u16* Ac, const u16* Bc, u16* An, u16* Bn, int k1,
    int wave, int lr, int qd, int wr, int wc,
    int rg, int sc, int aro, int wbA, f32x4 (&acc)[8][NF])
{
    bf16x8 b[NF][2];
    bf16x8 a[4][2];

    // ---------- phase 0: read B(all) + A-frags 0..3; stage ALL of t+1 -------
    #pragma unroll
    for (int nn = 0; nn < NF; nn++)
        #pragma unroll
        for (int ks = 0; ks < 2; ks++) {
            const int row = wc * (16 * NF) + nn * 16 + lr;
            b[nn][ks] = *(const bf16x8*)&Bc[row * 64 + (((ks * 4 + qd) ^ (row & 7)) * 8)];
        }
    LOADA4(0);
    if constexpr (ISS) {
        #pragma unroll
        for (int g = 0; g < NF; g++) SB(g, k1, Bn);
        SA(0, k1, An); SA(1, k1, An); SA(2, k1, An); SA(3, k1, An);
    }
    PHASE_SYNC();
    MFMAP4(0);
    waitvm<ISS ? NF + 4 : 0>();
    PHASE_END();
    // ---------- phase 1: read A-frags 4..7 ----------------------------------
    LOADA4(1);
    PHASE_SYNC();
    MFMAP4(1);
    if constexpr (ISS) waitvm<2>();
    PHASE_END();
}

// MODE 0: qkv epilogue (bf16 split store qk/vT), NF=3. MODE 1: f32 store, NF=2.
// Grid: 8 m-tiles x 32 n-tiles = 256 blocks. XCD patch: 2 m-groups x 4
// n-groups of XCDs; each XCD owns a 4m x 8n tile patch (min L2 fill).
template<int NF, int MODE>
__global__ __launch_bounds__(512, 2) void gemm256(
    const u16* __restrict__ A, const u16* __restrict__ BT,
    u16* __restrict__ qk, u16* __restrict__ vT, float* __restrict__ Cf)
{
    alignas(16) __shared__ u16 As[2][256 * 64];
    alignas(16) __shared__ u16 Bs[2][NF * 64 * 64];

    const int tid = threadIdx.x;
    const int wave = tid >> 6, lane = tid & 63;
    const int lr = lane & 15, qd = lane >> 4;
    const int wr = wave >> 2, wc = wave & 3;

    // XCD patch swizzle (bijective over 256 blocks)
    const int x = blockIdx.x & 7, bi = blockIdx.x >> 3;   // xcd, idx in [0,32)
    const int m0 = ((x & 1) * 4 + (bi & 3)) * 256;
    const int n0 = ((x >> 1) * 8 + (bi >> 2)) * (NF * 64);

    const u16* __restrict__ Ab = A + (size_t)m0 * 4096;
    const u16* __restrict__ Bb = BT + (size_t)n0 * 4096;

    // staging coords
    const int rg = tid >> 3;                        // 0..63
    const int sc = ((tid & 7) ^ (rg & 7)) * 8;      // pre-swizzled chunk (u16)
    const int aro = (rg < 32) ? rg : (96 + rg);     // interleaved A-group row
    const int wbA = (wave < 4) ? wave * 8 : (96 + wave * 8);

    f32x4 acc[8][NF];
    #pragma unroll
    for (int i = 0; i < 8; i++)
        #pragma unroll
        for (int j = 0; j < NF; j++) acc[i][j] = (f32x4){0.f, 0.f, 0.f, 0.f};

    // prologue: stage tile 0 in queue order [B0..B(NF-1), A0, A1, A2, A3]
    #pragma unroll
    for (int g = 0; g < NF; g++) SB(g, 0, &Bs[0][0]);
    SA(0, 0, &As[0][0]); SA(1, 0, &As[0][0]); SA(2, 0, &As[0][0]); SA(3, 0, &As[0][0]);
    waitvm<2>();                      // B(0), A0, A1 landed (ph0's needs)
    __builtin_amdgcn_s_barrier();
    __builtin_amdgcn_sched_barrier(0);

    // tiles 0..62 stage t+1; tile 63 drains. (K=4096, BK=64)
    for (int t = 0; t < 63; ++t) {
        const bool odd = t & 1;
        tile_body<NF, 1>(Ab, Bb,
                         odd ? &As[1][0] : &As[0][0], odd ? &Bs[1][0] : &Bs[0][0],
                         odd ? &As[0][0] : &As[1][0], odd ? &Bs[0][0] : &Bs[1][0],
                         (t + 1) * 64, wave, lr, qd, wr, wc, rg, sc, aro, wbA, acc);
    }
    tile_body<NF, 0>(Ab, Bb, &As[1][0], &Bs[1][0], &As[0][0], &Bs[0][0], 0,
                     wave, lr, qd, wr, wc, rg, sc, aro, wbA, acc);   // t = 63

    // epilogue: C/D layout col=lane&15, row=(lane>>4)*4+reg [m89/m91]
    #pragma unroll
    for (int i = 0; i < 8; i++)
        #pragma unroll
        for (int j = 0; j < NF; j++) {
            const int col = n0 + wc * (16 * NF) + j * 16 + lr;
            #pragma unroll
            for (int r = 0; r < 4; r++) {
                const int row = m0 + wr * 128 + i * 16 + qd * 4 + r;
                if constexpr (MODE == 0) {
                    const u16 val = f2bf(nanfix(acc[i][j][r], 1000.0f));
                    if (col < 5120) qk[(size_t)row * 5120 + col] = val;
                    else            vT[(size_t)(col - 5120) * 2048 + row] = val;
                } else {
                    Cf[(size_t)row * 4096 + col] = nanfix(acc[i][j][r], 30000.0f);
                }
            }
        }
}

#undef SB
#undef SA
#undef LOADA4
#undef MFMAP4
#undef PHASE_SYNC
#undef PHASE_END

// ---------------- NeoX RoPE in-place on qk (stride 5120) ----------------------
// 256 threads = 4 heads per block; grid (2048, 10).
__global__ void rope_k(u16* __restrict__ qk, const int* __restrict__ positions) {
    const int s = blockIdx.x;
    const int h = blockIdx.y * 4 + (threadIdx.x >> 6);  // 0..39
    const int t = threadIdx.x & 63;                      // pair index
    u16* base = qk + (size_t)s * 5120 + ((h < 32) ? h * 128 : 4096 + (h - 32) * 128);
    const float pos = (float)positions[s];
    const float freq = pos * exp2f(-(float)t * (19.931568569324174f / 64.f));
    const float c = cosf(freq), sn = sinf(freq);
    const float x1 = bf2f(base[t]), x2 = bf2f(base[t + 64]);
    base[t]      = f2bf(x1 * c - x2 * sn);
    base[t + 64] = f2bf(x2 * c + x1 * sn);
}

// ---------------- flash attention, window=1024, sink, GQA 4:1 ------------------
// grid (q-tile 32, head 32), 256 threads = 4 waves; wave owns 16 q-rows.
// K staged async w/ XOR chunk swizzle; V from vT w/ stride-72 LDS; Q direct.
__global__ __launch_bounds__(256) void attn_k(
    const u16* __restrict__ qk, const u16* __restrict__ vT,
    const float* __restrict__ sink, u16* __restrict__ out)
{
    alignas(16) __shared__ u16 Ks[64 * 128];    // slot = row*16 + (chunk ^ (row&15))
    alignas(16) __shared__ u16 VsT[128 * 72];   // [vd][seq], stride 72 (144B = 9x16B)
    alignas(16) __shared__ u16 Ps[4][16 * 72];

    const int h = blockIdx.y, hk = h >> 2;
    const int q0 = blockIdx.x * 64;
    const int tid = threadIdx.x, wave = tid >> 6, lane = tid & 63;
    const int lr = lane & 15, qd = lane >> 4;
    const float scaling = 0.08838834764831845f;  // 1/sqrt(128)

    // Q fragments straight from global (post-RoPE)
    bf16x8 aq[4];
    #pragma unroll
    for (int kc = 0; kc < 4; kc++)
        aq[kc] = *(const bf16x8*)&qk[(size_t)(q0 + wave * 16 + lr) * 5120 + h * 128 + kc * 32 + qd * 8];

    const float sinkv = sink[h];
    float m_run[4], l_run[4];
    #pragma unroll
    for (int r = 0; r < 4; r++) { m_run[r] = sinkv; l_run[r] = 0.f; }
    f32x4 acc_o[8];
    #pragma unroll
    for (int i = 0; i < 8; i++) acc_o[i] = (f32x4){0.f, 0.f, 0.f, 0.f};

    const int jlo = (q0 - 1023) > 0 ? (q0 - 1023) : 0;
    const int t0 = jlo >> 6, t1 = q0 >> 6;

    for (int kt = t0; kt <= t1; kt++) {
        const int j0 = kt * 64;
        __syncthreads();  // WAR: prior-iter Ks/VsT/Ps reads complete
        // K tile: 64 rows x 128 u16 = 1024 chunks of 16B, async, XOR-swizzled
        #pragma unroll
        for (int p = 0; p < 4; p++) {
            const int idx = p * 256 + tid;
            const int r = idx >> 4, cs = idx & 15, c = cs ^ (r & 15);
            async16(&qk[(size_t)(j0 + r) * 5120 + 4096 + hk * 128 + c * 8],
                    Ks + (p * 256 + wave * 64) * 8);
        }
        // V tile from vT: 128 vd-rows x 64 seq
        #pragma unroll
        for (int p = 0; p < 4; p++) {
            const int idx = p * 256 + tid;
            const int vd = idx >> 3, sc2 = (idx & 7) * 8;
            const u16x8 v = *(const u16x8*)&vT[(size_t)(hk * 128 + vd) * 2048 + j0 + sc2];
            *(u16x8*)&VsT[vd * 72 + sc2] = v;
        }
        __syncthreads();

        // S = Q K^T : per-wave 16x64
        float sv[4][4];
        #pragma unroll
        for (int nt = 0; nt < 4; nt++) {
            f32x4 s = (f32x4){0.f, 0.f, 0.f, 0.f};
            #pragma unroll
            for (int kc = 0; kc < 4; kc++) {
                const int krow = nt * 16 + lr;
                const bf16x8 bk = *(const bf16x8*)&Ks[(krow * 16 + ((kc * 4 + qd) ^ lr)) * 8];
                s = __builtin_amdgcn_mfma_f32_16x16x32_bf16(aq[kc], bk, s, 0, 0, 0);
            }
            #pragma unroll
            for (int r = 0; r < 4; r++) sv[nt][r] = s[r];
        }

        // mask + scale + rowmax (row = qd*4+r, col = nt*16+lr)
        float rmax[4] = {-1e30f, -1e30f, -1e30f, -1e30f};
        #pragma unroll
        for (int nt = 0; nt < 4; nt++) {
            const int kpos = j0 + nt * 16 + lr;
            #pragma unroll
            for (int r = 0; r < 4; r++) {
                const int qpos = q0 + wave * 16 + qd * 4 + r;
                const bool ok = (kpos <= qpos) && (qpos - kpos < 1024);
                const float x = ok ? sv[nt][r] * scaling : -1e30f;
                sv[nt][r] = x;
                rmax[r] = fmaxf(rmax[r], x);
            }
        }
        #pragma unroll
        for (int off = 1; off < 16; off <<= 1)
            #pragma unroll
            for (int r = 0; r < 4; r++)
                rmax[r] = fmaxf(rmax[r], __shfl_xor(rmax[r], off, 64));

        float alpha[4], rsum[4];
        #pragma unroll
        for (int r = 0; r < 4; r++) {
            const float mnew = fmaxf(m_run[r], rmax[r]);
            alpha[r] = __expf(m_run[r] - mnew);
            m_run[r] = mnew;
            rsum[r] = 0.f;
        }
        #pragma unroll
        for (int nt = 0; nt < 4; nt++)
            #pragma unroll
            for (int r = 0; r < 4; r++) {
                const float p = __expf(sv[nt][r] - m_run[r]);
                sv[nt][r] = p;
                rsum[r] += p;
            }
        #pragma unroll
        for (int off = 1; off < 16; off <<= 1)
            #pragma unroll
            for (int r = 0; r < 4; r++)
                rsum[r] += __shfl_xor(rsum[r], off, 64);
        #pragma unroll
        for (int r = 0; r < 4; r++)
            l_run[r] = l_run[r] * alpha[r] + rsum[r];

        // P (C-layout) -> LDS bridge (stride 72); barrier before A-layout read
        #pragma unroll
        for (int nt = 0; nt < 4; nt++)
            #pragma unroll
            for (int r = 0; r < 4; r++)
                Ps[wave][(qd * 4 + r) * 72 + nt * 16 + lr] = f2bf(sv[nt][r]);

        #pragma unroll
        for (int i = 0; i < 8; i++)
            #pragma unroll
            for (int r = 0; r < 4; r++) acc_o[i][r] *= alpha[r];

        __syncthreads();

        bf16x8 pa[2];
        #pragma unroll
        for (int kc = 0; kc < 2; kc++)
            pa[kc] = *(const bf16x8*)&Ps[wave][lr * 72 + kc * 32 + qd * 8];

        #pragma unroll
        for (int nt = 0; nt < 8; nt++)
            #pragma unroll
            for (int kc = 0; kc < 2; kc++) {
                const bf16x8 bv = *(const bf16x8*)&VsT[(nt * 16 + lr) * 72 + kc * 32 + qd * 8];
                acc_o[nt] = __builtin_amdgcn_mfma_f32_16x16x32_bf16(pa[kc], bv, acc_o[nt], 0, 0, 0);
            }
    }

    float invd[4];
    #pragma unroll
    for (int r = 0; r < 4; r++)
        invd[r] = 1.f / (l_run[r] + __expf(sinkv - m_run[r]));
    #pragma unroll
    for (int nt = 0; nt < 8; nt++) {
        const int col = h * 128 + nt * 16 + lr;
        #pragma unroll
        for (int r = 0; r < 4; r++) {
            const int row = q0 + wave * 16 + qd * 4 + r;
            out[(size_t)row * 4096 + col] = f2bf(nanfix(acc_o[nt][r] * invd[r], 8.0f));
        }
    }
}

extern "C" void kernel_launch(void* const* d_in, const int* in_sizes, int n_in,
                              void* d_out, int out_size, void* d_ws, size_t ws_size,
                              hipStream_t stream)
{
    (void)in_sizes; (void)n_in; (void)out_size; (void)ws_size;
    const float* hidden    = (const float*)d_in[0];
    const int*   positions = (const int*)d_in[1];
    const float* wq   = (const float*)d_in[2];
    const float* wk   = (const float*)d_in[3];
    const float* wv   = (const float*)d_in[4];
    const float* wo   = (const float*)d_in[5];
    const float* sink = (const float*)d_in[6];
    float* out = (float*)d_out;

    // Workspace (88 MB peak):
    //  [0,16M)   hiddenB (2048x4096 bf16)      -- dead after gemm_qkv
    //  [16,64M)  wqkvT (6144x4096 bf16)        -- dead after gemm_qkv
    //  [64,84M)  qk (2048x5120 bf16)
    //  [84,88M)  vT (1024x2048 bf16)
    //  reuse:    [0,32M) woT (4096x4096 bf16), [32,48M) attnB (2048x4096 bf16)
    char* ws = (char*)d_ws;
    u16* hiddenB = (u16*)(ws);
    u16* wqkvT   = (u16*)(ws + (size_t)16777216);
    u16* qk      = (u16*)(ws + (size_t)67108864);
    u16* vT      = (u16*)(ws + (size_t)88080384);
    u16* woT     = (u16*)(ws);
    u16* attnB   = (u16*)(ws + (size_t)33554432);

    // convert / transpose to bf16 (bandwidth passes)
    cvt_k <<<4096, 256, 0, stream>>>(hidden, hiddenB);
    cvtT_k<<<dim3(128, 128), dim3(32, 8), 0, stream>>>(wq, wqkvT, 4096, 4096);
    cvtT_k<<<dim3(32, 128),  dim3(32, 8), 0, stream>>>(wk, wqkvT + (size_t)4096 * 4096, 4096, 1024);
    cvtT_k<<<dim3(32, 128),  dim3(32, 8), 0, stream>>>(wv, wqkvT + (size_t)5120 * 4096, 4096, 1024);

    // fused QKV projection (q,k -> qk; v -> vT): 2048x6144, tiles 256x192,
    // grid 8x32 = 256 blocks (exact CU fill)
    gemm256<3, 0><<<256, 512, 0, stream>>>(hiddenB, wqkvT, qk, vT, nullptr);

    // wqkvT/hiddenB dead -> wo transpose into their space
    cvtT_k<<<dim3(128, 128), dim3(32, 8), 0, stream>>>(wo, woT, 4096, 4096);

    rope_k<<<dim3(2048, 10), 256, 0, stream>>>(qk, positions);
    attn_k<<<dim3(32, 32), 256, 0, stream>>>(qk, vT, sink, attnB);

    // out GEMM: 2048x4096, tiles 256x128, grid 8x32 = 256 blocks
    gemm256<2, 1><<<256, 512, 0, stream>>>(attnB, woT, nullptr, nullptr, out);
}

// Round 7
// 512.256 us; speedup vs baseline: 1.0454x; 1.0115x over previous
//
#include <hip/hip_runtime.h>
#include <cstdint>
#include <cstddef>

typedef uint16_t u16;
typedef __bf16 bf16x8 __attribute__((ext_vector_type(8)));
typedef float f32x4 __attribute__((ext_vector_type(4)));
typedef u16 u16x8 __attribute__((ext_vector_type(8)));

// ---- sizes (fixed) ----
// SEQ=2048 HIDDEN=4096 NQ=32 NKV=8 HD=128 WINDOW=1024
// fp32 inputs/output; bf16 MFMA compute with pre-converted bf16 operands.
// qk row layout: [q 4096 | k 1024] stride 5120; V kept transposed (vT).

__device__ __forceinline__ u16 f2bf(float f) {
    union { float f; uint32_t i; } v; v.f = f;
    uint32_t b = v.i;
    return (u16)((b + 0x7FFFu + ((b >> 16) & 1u)) >> 16);  // RNE
}
__device__ __forceinline__ float bf2f(u16 u) {
    union { uint32_t i; float f; } v; v.i = ((uint32_t)u) << 16; return v.f;
}
__device__ __forceinline__ float nanfix(float x, float repl) {
    return (x == x && fabsf(x) < 1e30f) ? x : repl;
}
// async global->LDS, 16B per lane; lds ptr must be wave-uniform base
// (lane i lands at base + i*16) [m97/m104].
__device__ __forceinline__ void async16(const u16* g, u16* l) {
    __builtin_amdgcn_global_load_lds(
        (const __attribute__((address_space(1))) uint32_t*)g,
        (__attribute__((address_space(3))) uint32_t*)l, 16, 0, 0);
}

template<int N> __device__ __forceinline__ void waitvm() {
    static_assert(N >= 0 && N <= 14, "vmcnt range");
    if constexpr (N == 0)  asm volatile("s_waitcnt vmcnt(0)" ::: "memory");
    else if constexpr (N == 1)  asm volatile("s_waitcnt vmcnt(1)" ::: "memory");
    else if constexpr (N == 2)  asm volatile("s_waitcnt vmcnt(2)" ::: "memory");
    else if constexpr (N == 3)  asm volatile("s_waitcnt vmcnt(3)" ::: "memory");
    else if constexpr (N == 4)  asm volatile("s_waitcnt vmcnt(4)" ::: "memory");
    else if constexpr (N == 5)  asm volatile("s_waitcnt vmcnt(5)" ::: "memory");
    else if constexpr (N == 6)  asm volatile("s_waitcnt vmcnt(6)" ::: "memory");
    else if constexpr (N == 7)  asm volatile("s_waitcnt vmcnt(7)" ::: "memory");
    else if constexpr (N == 8)  asm volatile("s_waitcnt vmcnt(8)" ::: "memory");
    else if constexpr (N == 9)  asm volatile("s_waitcnt vmcnt(9)" ::: "memory");
    else if constexpr (N == 10) asm volatile("s_waitcnt vmcnt(10)" ::: "memory");
    else if constexpr (N == 11) asm volatile("s_waitcnt vmcnt(11)" ::: "memory");
    else if constexpr (N == 12) asm volatile("s_waitcnt vmcnt(12)" ::: "memory");
    else if constexpr (N == 13) asm volatile("s_waitcnt vmcnt(13)" ::: "memory");
    else                        asm volatile("s_waitcnt vmcnt(14)" ::: "memory");
}

// ---------------- fp32 -> bf16 flat convert (n multiple of 2048*8) -----------
__global__ void cvt_k(const float* __restrict__ in, u16* __restrict__ out) {
    const size_t i = ((size_t)blockIdx.x * 256 + threadIdx.x) * 8;
    const f32x4 a = *(const f32x4*)&in[i], b = *(const f32x4*)&in[i + 4];
    u16x8 s;
    #pragma unroll
    for (int e = 0; e < 4; e++) { s[e] = f2bf(a[e]); s[4 + e] = f2bf(b[e]); }
    *(u16x8*)&out[i] = s;
}

// ---------- fp32 (R,C) -> bf16 (C,R) transpose+convert, 64x64 tiles ----------
// R7: vectorized — float4 loads, u16x8 (16B) stores. 256 threads.
// grid (C/64, R/64). R,C multiples of 64.
__global__ void cvtT_k(const float* __restrict__ in, u16* __restrict__ out,
                       int R, int C) {
    __shared__ float tile[64][65];
    const int bx = blockIdx.x * 64, by = blockIdx.y * 64;   // bx: col, by: row
    const int tid = threadIdx.x;
    const int lc = (tid & 15) * 4, lrw = tid >> 4;          // load coords
    #pragma unroll
    for (int i = 0; i < 4; i++) {
        const f32x4 v = *(const f32x4*)&in[(size_t)(by + lrw + i * 16) * C + bx + lc];
        tile[lrw + i * 16][lc]     = v[0];
        tile[lrw + i * 16][lc + 1] = v[1];
        tile[lrw + i * 16][lc + 2] = v[2];
        tile[lrw + i * 16][lc + 3] = v[3];
    }
    __syncthreads();
    #pragma unroll
    for (int p = 0; p < 2; p++) {
        const int c = (tid >> 3) + p * 32, r0 = (tid & 7) * 8;
        u16x8 s;
        #pragma unroll
        for (int e = 0; e < 8; e++) s[e] = f2bf(tile[r0 + e][c]);
        *(u16x8*)&out[(size_t)(bx + c) * R + by + r0] = s;
    }
}

// =====================================================================
// 256 x (64*NF) / BK=64 / 8-wave (2Mx4N) GEMM. (frozen from R6)
// TWO phases per K-tile. Phase P reads A-frags P*4..P*4+3 (+ all B in ph0)
// and runs 4*NF*2 MFMAs. Staging: ALL of tile t+1 issued at ph0 into the
// other-parity buffer. Queue-sim waits: steady ph0 NF+4, ph1 2; drain 0.
// LDS swizzle: LDS[r][c]=global[r][c^(r&7)] via pre-swizzled global source
// (global_load_lds dest lane-linear) + swizzled ds_read (rule #21).
// =====================================================================

#define SB(g, kk, dst) async16(Bb + (size_t)((g) * 64 + rg) * 4096 + (kk) + sc, \
                               (dst) + ((g) * 64 + wave * 8) * 64)
#define SA(g, kk, dst) async16(Ab + (size_t)((g) * 32 + aro) * 4096 + (kk) + sc, \
                               (dst) + ((g) * 32 + wbA) * 64)

#define LOADA4(PH) do {                                                         \
    _Pragma("unroll")                                                           \
    for (int f = 0; f < 4; f++) {                                               \
        const int row = wr * 128 + ((PH) * 4 + f) * 16 + lr;                    \
        _Pragma("unroll")                                                       \
        for (int ks = 0; ks < 2; ks++)                                          \
            a[f][ks] = *(const bf16x8*)&Ac[row * 64 + (((ks * 4 + qd) ^ (row & 7)) * 8)]; \
    }                                                                           \
} while (0)

#define MFMAP4(PH) do {                                                         \
    __builtin_amdgcn_s_setprio(1);                                              \
    _Pragma("unroll")                                                           \
    for (int f = 0; f < 4; f++)                                                 \
        _Pragma("unroll")                                                       \
        for (int nn = 0; nn < NF; nn++)                                         \
            _Pragma("unroll")                                                   \
            for (int ks = 0; ks < 2; ks++)                                      \
                acc[(PH) * 4 + f][nn] = __builtin_amdgcn_mfma_f32_16x16x32_bf16(\
                    a[f][ks], b[nn][ks], acc[(PH) * 4 + f][nn], 0, 0, 0);       \
    __builtin_amdgcn_s_setprio(0);                                              \
} while (0)

#define PHASE_SYNC() do {                                                       \
    __builtin_amdgcn_s_barrier();                                               \
    asm volatile("s_waitcnt lgkmcnt(0)" ::: "memory");                          \
    __builtin_amdgcn_sched_barrier(0);                                          \
} while (0)

#define PHASE_END() do {                                                        \
    __builtin_amdgcn_s_barrier();                                               \
    __builtin_amdgcn_sched_barrier(0);                                          \
} while (0)

// ISS: 1 = stage tile t+1 (k1) into An/Bn at ph0; 0 = last tile (drain).
template<int NF, int ISS>
__device__ __forceinline__ void tile_body(
    const u16* __restrict__ Ab, const u16* __restrict__ Bb,
    const u16* Ac, const u16* Bc, u16* An, u16* Bn, int k1,
    int wave, int lr, int qd, int wr, int wc,
    int rg, int sc, int aro, int wbA, f32x4 (&acc)[8][NF])
{
    bf16x8 b[NF][2];
    bf16x8 a[4][2];

    // ---------- phase 0: read B(all) + A-frags 0..3; stage ALL of t+1 -------
    #pragma unroll
    for (int nn = 0; nn < NF; nn++)
        #pragma unroll
        for (int ks = 0; ks < 2; ks++) {
            const int row = wc * (16 * NF) + nn * 16 + lr;
            b[nn][ks] = *(const bf16x8*)&Bc[row * 64 + (((ks * 4 + qd) ^ (row & 7)) * 8)];
        }
    LOADA4(0);
    if constexpr (ISS) {
        #pragma unroll
        for (int g = 0; g < NF; g++) SB(g, k1, Bn);
        SA(0, k1, An); SA(1, k1, An); SA(2, k1, An); SA(3, k1, An);
    }
    PHASE_SYNC();
    MFMAP4(0);
    waitvm<ISS ? NF + 4 : 0>();
    PHASE_END();
    // ---------- phase 1: read A-frags 4..7 ----------------------------------
    LOADA4(1);
    PHASE_SYNC();
    MFMAP4(1);
    if constexpr (ISS) waitvm<2>();
    PHASE_END();
}

// MODE 0: qkv epilogue (bf16 split store qk/vT), NF=3. MODE 1: f32 store, NF=2.
// Grid: 8 m-tiles x 32 n-tiles = 256 blocks. XCD patch: 2 m-groups x 4
// n-groups of XCDs; each XCD owns a 4m x 8n tile patch (min L2 fill).
template<int NF, int MODE>
__global__ __launch_bounds__(512, 2) void gemm256(
    const u16* __restrict__ A, const u16* __restrict__ BT,
    u16* __restrict__ qk, u16* __restrict__ vT, float* __restrict__ Cf)
{
    alignas(16) __shared__ u16 As[2][256 * 64];
    alignas(16) __shared__ u16 Bs[2][NF * 64 * 64];

    const int tid = threadIdx.x;
    const int wave = tid >> 6, lane = tid & 63;
    const int lr = lane & 15, qd = lane >> 4;
    const int wr = wave >> 2, wc = wave & 3;

    // XCD patch swizzle (bijective over 256 blocks)
    const int x = blockIdx.x & 7, bi = blockIdx.x >> 3;   // xcd, idx in [0,32)
    const int m0 = ((x & 1) * 4 + (bi & 3)) * 256;
    const int n0 = ((x >> 1) * 8 + (bi >> 2)) * (NF * 64);

    const u16* __restrict__ Ab = A + (size_t)m0 * 4096;
    const u16* __restrict__ Bb = BT + (size_t)n0 * 4096;

    // staging coords
    const int rg = tid >> 3;                        // 0..63
    const int sc = ((tid & 7) ^ (rg & 7)) * 8;      // pre-swizzled chunk (u16)
    const int aro = (rg < 32) ? rg : (96 + rg);     // interleaved A-group row
    const int wbA = (wave < 4) ? wave * 8 : (96 + wave * 8);

    f32x4 acc[8][NF];
    #pragma unroll
    for (int i = 0; i < 8; i++)
        #pragma unroll
        for (int j = 0; j < NF; j++) acc[i][j] = (f32x4){0.f, 0.f, 0.f, 0.f};

    // prologue: stage tile 0 in queue order [B0..B(NF-1), A0, A1, A2, A3]
    #pragma unroll
    for (int g = 0; g < NF; g++) SB(g, 0, &Bs[0][0]);
    SA(0, 0, &As[0][0]); SA(1, 0, &As[0][0]); SA(2, 0, &As[0][0]); SA(3, 0, &As[0][0]);
    waitvm<2>();                      // B(0), A0, A1 landed (ph0's needs)
    __builtin_amdgcn_s_barrier();
    __builtin_amdgcn_sched_barrier(0);

    // tiles 0..62 stage t+1; tile 63 drains. (K=4096, BK=64)
    for (int t = 0; t < 63; ++t) {
        const bool odd = t & 1;
        tile_body<NF, 1>(Ab, Bb,
                         odd ? &As[1][0] : &As[0][0], odd ? &Bs[1][0] : &Bs[0][0],
                         odd ? &As[0][0] : &As[1][0], odd ? &Bs[0][0] : &Bs[1][0],
                         (t + 1) * 64, wave, lr, qd, wr, wc, rg, sc, aro, wbA, acc);
    }
    tile_body<NF, 0>(Ab, Bb, &As[1][0], &Bs[1][0], &As[0][0], &Bs[0][0], 0,
                     wave, lr, qd, wr, wc, rg, sc, aro, wbA, acc);   // t = 63

    // epilogue: C/D layout col=lane&15, row=(lane>>4)*4+reg [m89/m91]
    #pragma unroll
    for (int i = 0; i < 8; i++)
        #pragma unroll
        for (int j = 0; j < NF; j++) {
            const int col = n0 + wc * (16 * NF) + j * 16 + lr;
            #pragma unroll
            for (int r = 0; r < 4; r++) {
                const int row = m0 + wr * 128 + i * 16 + qd * 4 + r;
                if constexpr (MODE == 0) {
                    const u16 val = f2bf(nanfix(acc[i][j][r], 1000.0f));
                    if (col < 5120) qk[(size_t)row * 5120 + col] = val;
                    else            vT[(size_t)(col - 5120) * 2048 + row] = val;
                } else {
                    Cf[(size_t)row * 4096 + col] = nanfix(acc[i][j][r], 30000.0f);
                }
            }
        }
}

#undef SB
#undef SA
#undef LOADA4
#undef MFMAP4
#undef PHASE_SYNC
#undef PHASE_END

// ---------------- NeoX RoPE in-place on qk (stride 5120) ----------------------
// 256 threads = 4 heads per block; grid (2048, 10).
__global__ void rope_k(u16* __restrict__ qk, const int* __restrict__ positions) {
    const int s = blockIdx.x;
    const int h = blockIdx.y * 4 + (threadIdx.x >> 6);  // 0..39
    const int t = threadIdx.x & 63;                      // pair index
    u16* base = qk + (size_t)s * 5120 + ((h < 32) ? h * 128 : 4096 + (h - 32) * 128);
    const float pos = (float)positions[s];
    const float freq = pos * exp2f(-(float)t * (19.931568569324174f / 64.f));
    const float c = cosf(freq), sn = sinf(freq);
    const float x1 = bf2f(base[t]), x2 = bf2f(base[t + 64]);
    base[t]      = f2bf(x1 * c - x2 * sn);
    base[t + 64] = f2bf(x2 * c + x1 * sn);
}

// ---------------- flash attention, window=1024, sink, GQA 4:1 ------------------
// grid (q-tile 32, head 32), 256 threads = 4 waves; wave owns 16 q-rows.
// K staged async w/ XOR chunk swizzle; V from vT w/ stride-72 LDS; Q direct.
// R7: mid-tile __syncthreads removed — Ps is per-wave (write+read by the
// same wave), so lgkmcnt(0) suffices; waves skew between softmax and PV.
__global__ __launch_bounds__(256) void attn_k(
    const u16* __restrict__ qk, const u16* __restrict__ vT,
    const float* __restrict__ sink, u16* __restrict__ out)
{
    alignas(16) __shared__ u16 Ks[64 * 128];    // slot = row*16 + (chunk ^ (row&15))
    alignas(16) __shared__ u16 VsT[128 * 72];   // [vd][seq], stride 72 (144B = 9x16B)
    alignas(16) __shared__ u16 Ps[4][16 * 72];

    const int h = blockIdx.y, hk = h >> 2;
    const int q0 = blockIdx.x * 64;
    const int tid = threadIdx.x, wave = tid >> 6, lane = tid & 63;
    const int lr = lane & 15, qd = lane >> 4;
    const float scaling = 0.08838834764831845f;  // 1/sqrt(128)

    // Q fragments straight from global (post-RoPE)
    bf16x8 aq[4];
    #pragma unroll
    for (int kc = 0; kc < 4; kc++)
        aq[kc] = *(const bf16x8*)&qk[(size_t)(q0 + wave * 16 + lr) * 5120 + h * 128 + kc * 32 + qd * 8];

    const float sinkv = sink[h];
    float m_run[4], l_run[4];
    #pragma unroll
    for (int r = 0; r < 4; r++) { m_run[r] = sinkv; l_run[r] = 0.f; }
    f32x4 acc_o[8];
    #pragma unroll
    for (int i = 0; i < 8; i++) acc_o[i] = (f32x4){0.f, 0.f, 0.f, 0.f};

    const int jlo = (q0 - 1023) > 0 ? (q0 - 1023) : 0;
    const int t0 = jlo >> 6, t1 = q0 >> 6;

    for (int kt = t0; kt <= t1; kt++) {
        const int j0 = kt * 64;
        __syncthreads();  // WAR: prior-iter Ks/VsT reads complete
        // K tile: 64 rows x 128 u16 = 1024 chunks of 16B, async, XOR-swizzled
        #pragma unroll
        for (int p = 0; p < 4; p++) {
            const int idx = p * 256 + tid;
            const int r = idx >> 4, cs = idx & 15, c = cs ^ (r & 15);
            async16(&qk[(size_t)(j0 + r) * 5120 + 4096 + hk * 128 + c * 8],
                    Ks + (p * 256 + wave * 64) * 8);
        }
        // V tile from vT: 128 vd-rows x 64 seq
        #pragma unroll
        for (int p = 0; p < 4; p++) {
            const int idx = p * 256 + tid;
            const int vd = idx >> 3, sc2 = (idx & 7) * 8;
            const u16x8 v = *(const u16x8*)&vT[(size_t)(hk * 128 + vd) * 2048 + j0 + sc2];
            *(u16x8*)&VsT[vd * 72 + sc2] = v;
        }
        __syncthreads();  // RAW: K (vmcnt drained here) + V visible to all waves

        // S = Q K^T : per-wave 16x64
        float sv[4][4];
        #pragma unroll
        for (int nt = 0; nt < 4; nt++) {
            f32x4 s = (f32x4){0.f, 0.f, 0.f, 0.f};
            #pragma unroll
            for (int kc = 0; kc < 4; kc++) {
                const int krow = nt * 16 + lr;
                const bf16x8 bk = *(const bf16x8*)&Ks[(krow * 16 + ((kc * 4 + qd) ^ lr)) * 8];
                s = __builtin_amdgcn_mfma_f32_16x16x32_bf16(aq[kc], bk, s, 0, 0, 0);
            }
            #pragma unroll
            for (int r = 0; r < 4; r++) sv[nt][r] = s[r];
        }

        // mask + scale + rowmax (row = qd*4+r, col = nt*16+lr)
        float rmax[4] = {-1e30f, -1e30f, -1e30f, -1e30f};
        #pragma unroll
        for (int nt = 0; nt < 4; nt++) {
            const int kpos = j0 + nt * 16 + lr;
            #pragma unroll
            for (int r = 0; r < 4; r++) {
                const int qpos = q0 + wave * 16 + qd * 4 + r;
                const bool ok = (kpos <= qpos) && (qpos - kpos < 1024);
                const float x = ok ? sv[nt][r] * scaling : -1e30f;
                sv[nt][r] = x;
                rmax[r] = fmaxf(rmax[r], x);
            }
        }
        #pragma unroll
        for (int off = 1; off < 16; off <<= 1)
            #pragma unroll
            for (int r = 0; r < 4; r++)
                rmax[r] = fmaxf(rmax[r], __shfl_xor(rmax[r], off, 64));

        float alpha[4], rsum[4];
        #pragma unroll
        for (int r = 0; r < 4; r++) {
            const float mnew = fmaxf(m_run[r], rmax[r]);
            alpha[r] = __expf(m_run[r] - mnew);
            m_run[r] = mnew;
            rsum[r] = 0.f;
        }
        #pragma unroll
        for (int nt = 0; nt < 4; nt++)
            #pragma unroll
            for (int r = 0; r < 4; r++) {
                const float p = __expf(sv[nt][r] - m_run[r]);
                sv[nt][r] = p;
                rsum[r] += p;
            }
        #pragma unroll
        for (int off = 1; off < 16; off <<= 1)
            #pragma unroll
            for (int r = 0; r < 4; r++)
                rsum[r] += __shfl_xor(rsum[r], off, 64);
        #pragma unroll
        for (int r = 0; r < 4; r++)
            l_run[r] = l_run[r] * alpha[r] + rsum[r];

        // P (C-layout) -> LDS bridge (stride 72); per-wave buffer, so only
        // this wave's ds_writes need to drain before its own ds_reads.
        #pragma unroll
        for (int nt = 0; nt < 4; nt++)
            #pragma unroll
            for (int r = 0; r < 4; r++)
                Ps[wave][(qd * 4 + r) * 72 + nt * 16 + lr] = f2bf(sv[nt][r]);

        #pragma unroll
        for (int i = 0; i < 8; i++)
            #pragma unroll
            for (int r = 0; r < 4; r++) acc_o[i][r] *= alpha[r];

        asm volatile("s_waitcnt lgkmcnt(0)" ::: "memory");
        __builtin_amdgcn_sched_barrier(0);

        bf16x8 pa[2];
        #pragma unroll
        for (int kc = 0; kc < 2; kc++)
            pa[kc] = *(const bf16x8*)&Ps[wave][lr * 72 + kc * 32 + qd * 8];

        #pragma unroll
        for (int nt = 0; nt < 8; nt++)
            #pragma unroll
            for (int kc = 0; kc < 2; kc++) {
                const bf16x8 bv = *(const bf16x8*)&VsT[(nt * 16 + lr) * 72 + kc * 32 + qd * 8];
                acc_o[nt] = __builtin_amdgcn_mfma_f32_16x16x32_bf16(pa[kc], bv, acc_o[nt], 0, 0, 0);
            }
    }

    float invd[4];
    #pragma unroll
    for (int r = 0; r < 4; r++)
        invd[r] = 1.f / (l_run[r] + __expf(sinkv - m_run[r]));
    #pragma unroll
    for (int nt = 0; nt < 8; nt++) {
        const int col = h * 128 + nt * 16 + lr;
        #pragma unroll
        for (int r = 0; r < 4; r++) {
            const int row = q0 + wave * 16 + qd * 4 + r;
            out[(size_t)row * 4096 + col] = f2bf(nanfix(acc_o[nt][r] * invd[r], 8.0f));
        }
    }
}

extern "C" void kernel_launch(void* const* d_in, const int* in_sizes, int n_in,
                              void* d_out, int out_size, void* d_ws, size_t ws_size,
                              hipStream_t stream)
{
    (void)in_sizes; (void)n_in; (void)out_size; (void)ws_size;
    const float* hidden    = (const float*)d_in[0];
    const int*   positions = (const int*)d_in[1];
    const float* wq   = (const float*)d_in[2];
    const float* wk   = (const float*)d_in[3];
    const float* wv   = (const float*)d_in[4];
    const float* wo   = (const float*)d_in[5];
    const float* sink = (const float*)d_in[6];
    float* out = (float*)d_out;

    // Workspace (88 MB peak):
    //  [0,16M)   hiddenB (2048x4096 bf16)      -- dead after gemm_qkv
    //  [16,64M)  wqkvT (6144x4096 bf16)        -- dead after gemm_qkv
    //  [64,84M)  qk (2048x5120 bf16)
    //  [84,88M)  vT (1024x2048 bf16)
    //  reuse:    [0,32M) woT (4096x4096 bf16), [32,48M) attnB (2048x4096 bf16)
    char* ws = (char*)d_ws;
    u16* hiddenB = (u16*)(ws);
    u16* wqkvT   = (u16*)(ws + (size_t)16777216);
    u16* qk      = (u16*)(ws + (size_t)67108864);
    u16* vT      = (u16*)(ws + (size_t)88080384);
    u16* woT     = (u16*)(ws);
    u16* attnB   = (u16*)(ws + (size_t)33554432);

    // convert / transpose to bf16 (bandwidth passes)
    cvt_k <<<4096, 256, 0, stream>>>(hidden, hiddenB);
    cvtT_k<<<dim3(64, 64), 256, 0, stream>>>(wq, wqkvT, 4096, 4096);
    cvtT_k<<<dim3(16, 64), 256, 0, stream>>>(wk, wqkvT + (size_t)4096 * 4096, 4096, 1024);
    cvtT_k<<<dim3(16, 64), 256, 0, stream>>>(wv, wqkvT + (size_t)5120 * 4096, 4096, 1024);

    // fused QKV projection (q,k -> qk; v -> vT): 2048x6144, tiles 256x192,
    // grid 8x32 = 256 blocks (exact CU fill)
    gemm256<3, 0><<<256, 512, 0, stream>>>(hiddenB, wqkvT, qk, vT, nullptr);

    // wqkvT/hiddenB dead -> wo transpose into their space
    cvtT_k<<<dim3(64, 64), 256, 0, stream>>>(wo, woT, 4096, 4096);

    rope_k<<<dim3(2048, 10), 256, 0, stream>>>(qk, positions);
    attn_k<<<dim3(32, 32), 256, 0, stream>>>(qk, vT, sink, attnB);

    // out GEMM: 2048x4096, tiles 256x128, grid 8x32 = 256 blocks
    gemm256<2, 1><<<256, 512, 0, stream>>>(attnB, woT, nullptr, nullptr, out);
}

// Round 8
// 507.453 us; speedup vs baseline: 1.0553x; 1.0095x over previous
//
#include <hip/hip_runtime.h>
#include <cstdint>
#include <cstddef>

typedef uint16_t u16;
typedef __bf16 bf16x8 __attribute__((ext_vector_type(8)));
typedef float f32x4 __attribute__((ext_vector_type(4)));
typedef u16 u16x8 __attribute__((ext_vector_type(8)));

// ---- sizes (fixed) ----
// SEQ=2048 HIDDEN=4096 NQ=32 NKV=8 HD=128 WINDOW=1024
// fp32 inputs/output; bf16 MFMA compute with pre-converted bf16 operands.
// qk row layout: [q 4096 | k 1024] stride 5120; V kept transposed (vT).

__device__ __forceinline__ u16 f2bf(float f) {
    union { float f; uint32_t i; } v; v.f = f;
    uint32_t b = v.i;
    return (u16)((b + 0x7FFFu + ((b >> 16) & 1u)) >> 16);  // RNE
}
__device__ __forceinline__ float bf2f(u16 u) {
    union { uint32_t i; float f; } v; v.i = ((uint32_t)u) << 16; return v.f;
}
__device__ __forceinline__ float nanfix(float x, float repl) {
    return (x == x && fabsf(x) < 1e30f) ? x : repl;
}
// async global->LDS, 16B per lane; lds ptr must be wave-uniform base
// (lane i lands at base + i*16) [m97/m104].
__device__ __forceinline__ void async16(const u16* g, u16* l) {
    __builtin_amdgcn_global_load_lds(
        (const __attribute__((address_space(1))) uint32_t*)g,
        (__attribute__((address_space(3))) uint32_t*)l, 16, 0, 0);
}

template<int N> __device__ __forceinline__ void waitvm() {
    static_assert(N >= 0 && N <= 14, "vmcnt range");
    if constexpr (N == 0)  asm volatile("s_waitcnt vmcnt(0)" ::: "memory");
    else if constexpr (N == 1)  asm volatile("s_waitcnt vmcnt(1)" ::: "memory");
    else if constexpr (N == 2)  asm volatile("s_waitcnt vmcnt(2)" ::: "memory");
    else if constexpr (N == 3)  asm volatile("s_waitcnt vmcnt(3)" ::: "memory");
    else if constexpr (N == 4)  asm volatile("s_waitcnt vmcnt(4)" ::: "memory");
    else if constexpr (N == 5)  asm volatile("s_waitcnt vmcnt(5)" ::: "memory");
    else if constexpr (N == 6)  asm volatile("s_waitcnt vmcnt(6)" ::: "memory");
    else if constexpr (N == 7)  asm volatile("s_waitcnt vmcnt(7)" ::: "memory");
    else if constexpr (N == 8)  asm volatile("s_waitcnt vmcnt(8)" ::: "memory");
    else if constexpr (N == 9)  asm volatile("s_waitcnt vmcnt(9)" ::: "memory");
    else if constexpr (N == 10) asm volatile("s_waitcnt vmcnt(10)" ::: "memory");
    else if constexpr (N == 11) asm volatile("s_waitcnt vmcnt(11)" ::: "memory");
    else if constexpr (N == 12) asm volatile("s_waitcnt vmcnt(12)" ::: "memory");
    else if constexpr (N == 13) asm volatile("s_waitcnt vmcnt(13)" ::: "memory");
    else                        asm volatile("s_waitcnt vmcnt(14)" ::: "memory");
}

// ---------------- fp32 -> bf16 flat convert (n multiple of 2048*8) -----------
__global__ void cvt_k(const float* __restrict__ in, u16* __restrict__ out) {
    const size_t i = ((size_t)blockIdx.x * 256 + threadIdx.x) * 8;
    const f32x4 a = *(const f32x4*)&in[i], b = *(const f32x4*)&in[i + 4];
    u16x8 s;
    #pragma unroll
    for (int e = 0; e < 4; e++) { s[e] = f2bf(a[e]); s[4 + e] = f2bf(b[e]); }
    *(u16x8*)&out[i] = s;
}

// ---------- fp32 (R,C) -> bf16 (C,R) transpose+convert, 64x64 tiles ----------
// vectorized — float4 loads, u16x8 (16B) stores. 256 threads.
// grid (C/64, R/64). R,C multiples of 64.
__global__ void cvtT_k(const float* __restrict__ in, u16* __restrict__ out,
                       int R, int C) {
    __shared__ float tile[64][65];
    const int bx = blockIdx.x * 64, by = blockIdx.y * 64;   // bx: col, by: row
    const int tid = threadIdx.x;
    const int lc = (tid & 15) * 4, lrw = tid >> 4;          // load coords
    #pragma unroll
    for (int i = 0; i < 4; i++) {
        const f32x4 v = *(const f32x4*)&in[(size_t)(by + lrw + i * 16) * C + bx + lc];
        tile[lrw + i * 16][lc]     = v[0];
        tile[lrw + i * 16][lc + 1] = v[1];
        tile[lrw + i * 16][lc + 2] = v[2];
        tile[lrw + i * 16][lc + 3] = v[3];
    }
    __syncthreads();
    #pragma unroll
    for (int p = 0; p < 2; p++) {
        const int c = (tid >> 3) + p * 32, r0 = (tid & 7) * 8;
        u16x8 s;
        #pragma unroll
        for (int e = 0; e < 8; e++) s[e] = f2bf(tile[r0 + e][c]);
        *(u16x8*)&out[(size_t)(bx + c) * R + by + r0] = s;
    }
}

// =====================================================================
// R8: 128 x (64*NF) / BK=64 / 4-wave (1Mx4N) GEMM, 64KB LDS -> 2 blocks/CU.
// Same proven phase skeleton (R6): per phase {ds_read frags ; issue stage}
//   -> s_barrier -> lgkmcnt(0)+sched_barrier(0) -> setprio(1) MFMA setprio(0)
//   -> counted waitvm -> s_barrier.
// Mechanism change: cross-BLOCK overlap (m114) — with 2 blocks/CU, one
// block's barrier drain is hidden by the other block's MFMA waves.
// Staging groups = 32 rows (4KB per 256-thread async16 call). Per tile:
// G = 2NF+4 loads [B0..B(2NF-1), A0..A3], ALL issued at ph0 into the
// other-parity buffer. A-groups {0,1} feed ph0 (frag rows 0-63),
// {2,3} feed ph1. Queue-sim waits: steady {2NF+4, 2}; drain {0,-};
// prologue 2. LDS swizzle: LDS[r][c]=global[r][c^(r&7)] via pre-swizzled
// global source + swizzled ds_read (rule #21).
// =====================================================================

#define SB(g, kk, dst) async16(Bb + (size_t)((g) * 32 + rg) * 4096 + (kk) + sc, \
                               (dst) + ((g) * 32 + wave * 8) * 64)
#define SA(g, kk, dst) async16(Ab + (size_t)((g) * 32 + rg) * 4096 + (kk) + sc, \
                               (dst) + ((g) * 32 + wave * 8) * 64)

#define LOADA4(PH) do {                                                         \
    _Pragma("unroll")                                                           \
    for (int f = 0; f < 4; f++) {                                               \
        const int row = ((PH) * 4 + f) * 16 + lr;                               \
        _Pragma("unroll")                                                       \
        for (int ks = 0; ks < 2; ks++)                                          \
            a[f][ks] = *(const bf16x8*)&Ac[row * 64 + (((ks * 4 + qd) ^ (row & 7)) * 8)]; \
    }                                                                           \
} while (0)

#define MFMAP4(PH) do {                                                         \
    __builtin_amdgcn_s_setprio(1);                                              \
    _Pragma("unroll")                                                           \
    for (int f = 0; f < 4; f++)                                                 \
        _Pragma("unroll")                                                       \
        for (int nn = 0; nn < NF; nn++)                                         \
            _Pragma("unroll")                                                   \
            for (int ks = 0; ks < 2; ks++)                                      \
                acc[(PH) * 4 + f][nn] = __builtin_amdgcn_mfma_f32_16x16x32_bf16(\
                    a[f][ks], b[nn][ks], acc[(PH) * 4 + f][nn], 0, 0, 0);       \
    __builtin_amdgcn_s_setprio(0);                                              \
} while (0)

#define PHASE_SYNC() do {                                                       \
    __builtin_amdgcn_s_barrier();                                               \
    asm volatile("s_waitcnt lgkmcnt(0)" ::: "memory");                          \
    __builtin_amdgcn_sched_barrier(0);                                          \
} while (0)

#define PHASE_END() do {                                                        \
    __builtin_amdgcn_s_barrier();                                               \
    __builtin_amdgcn_sched_barrier(0);                                          \
} while (0)

// ISS: 1 = stage tile t+1 (k1) into An/Bn at ph0; 0 = last tile (drain).
template<int NF, int ISS>
__device__ __forceinline__ void tile_body(
    const u16* __restrict__ Ab, const u16* __restrict__ Bb,
    const u16* Ac, const u16* Bc, u16* An, u16* Bn, int k1,
    int wave, int lr, int qd, int wc,
    int rg, int sc, f32x4 (&acc)[8][NF])
{
    bf16x8 b[NF][2];
    bf16x8 a[4][2];

    // ---------- phase 0: read B(all) + A-frags 0..3; stage ALL of t+1 -------
    #pragma unroll
    for (int nn = 0; nn < NF; nn++)
        #pragma unroll
        for (int ks = 0; ks < 2; ks++) {
            const int row = wc * (16 * NF) + nn * 16 + lr;
            b[nn][ks] = *(const bf16x8*)&Bc[row * 64 + (((ks * 4 + qd) ^ (row & 7)) * 8)];
        }
    LOADA4(0);
    if constexpr (ISS) {
        #pragma unroll
        for (int g = 0; g < 2 * NF; g++) SB(g, k1, Bn);
        SA(0, k1, An); SA(1, k1, An); SA(2, k1, An); SA(3, k1, An);
    }
    PHASE_SYNC();
    MFMAP4(0);
    waitvm<ISS ? 2 * NF + 4 : 0>();
    PHASE_END();
    // ---------- phase 1: read A-frags 4..7 ----------------------------------
    LOADA4(1);
    PHASE_SYNC();
    MFMAP4(1);
    if constexpr (ISS) waitvm<2>();
    PHASE_END();
}

// MODE 0: qkv epilogue (bf16 split store qk/vT), NTN=48. MODE 1: f32, NTN=32.
// NF=2 both: tile 128x128, LDS 64KB -> 2 blocks/CU.
// Grid: 16 m-tiles x NTN n-tiles. XCD patch: 4 XCD-m groups x 2 XCD-n
// groups; each XCD owns a 4m x (NTN/2)n patch (bijective).
template<int NF, int MODE>
__global__ __launch_bounds__(256, 2) void gemm256(
    const u16* __restrict__ A, const u16* __restrict__ BT,
    u16* __restrict__ qk, u16* __restrict__ vT, float* __restrict__ Cf)
{
    alignas(16) __shared__ u16 As[2][128 * 64];
    alignas(16) __shared__ u16 Bs[2][NF * 64 * 64];

    constexpr int NTN = (MODE == 0) ? 48 : 32;

    const int tid = threadIdx.x;
    const int wave = tid >> 6, lane = tid & 63;
    const int lr = lane & 15, qd = lane >> 4;
    const int wc = wave;                              // 1M x 4N wave grid

    // XCD patch swizzle (bijective)
    const int x = blockIdx.x & 7, bi = blockIdx.x >> 3;
    const int mi = (x & 3) * 4 + (bi & 3);            // [0,16)
    const int ni = (x >> 2) * (NTN / 2) + (bi >> 2);  // [0,NTN)
    const int m0 = mi * 128, n0 = ni * (NF * 64);

    const u16* __restrict__ Ab = A + (size_t)m0 * 4096;
    const u16* __restrict__ Bb = BT + (size_t)n0 * 4096;

    // staging coords (256 threads: rg in [0,32), 32-row groups)
    const int rg = tid >> 3;
    const int sc = ((tid & 7) ^ (rg & 7)) * 8;        // pre-swizzled chunk (u16)

    f32x4 acc[8][NF];
    #pragma unroll
    for (int i = 0; i < 8; i++)
        #pragma unroll
        for (int j = 0; j < NF; j++) acc[i][j] = (f32x4){0.f, 0.f, 0.f, 0.f};

    // prologue: stage tile 0 in queue order [B0..B(2NF-1), A0..A3]
    #pragma unroll
    for (int g = 0; g < 2 * NF; g++) SB(g, 0, &Bs[0][0]);
    SA(0, 0, &As[0][0]); SA(1, 0, &As[0][0]); SA(2, 0, &As[0][0]); SA(3, 0, &As[0][0]);
    waitvm<2>();                      // B(0), A0, A1 landed (ph0's needs)
    __builtin_amdgcn_s_barrier();
    __builtin_amdgcn_sched_barrier(0);

    // tiles 0..62 stage t+1; tile 63 drains. (K=4096, BK=64)
    for (int t = 0; t < 63; ++t) {
        const bool odd = t & 1;
        tile_body<NF, 1>(Ab, Bb,
                         odd ? &As[1][0] : &As[0][0], odd ? &Bs[1][0] : &Bs[0][0],
                         odd ? &As[0][0] : &As[1][0], odd ? &Bs[0][0] : &Bs[1][0],
                         (t + 1) * 64, wave, lr, qd, wc, rg, sc, acc);
    }
    tile_body<NF, 0>(Ab, Bb, &As[1][0], &Bs[1][0], &As[0][0], &Bs[0][0], 0,
                     wave, lr, qd, wc, rg, sc, acc);   // t = 63

    // epilogue: C/D layout col=lane&15, row=(lane>>4)*4+reg [m89/m91]
    #pragma unroll
    for (int i = 0; i < 8; i++)
        #pragma unroll
        for (int j = 0; j < NF; j++) {
            const int col = n0 + wc * (16 * NF) + j * 16 + lr;
            #pragma unroll
            for (int r = 0; r < 4; r++) {
                const int row = m0 + i * 16 + qd * 4 + r;
                if constexpr (MODE == 0) {
                    const u16 val = f2bf(nanfix(acc[i][j][r], 1000.0f));
                    if (col < 5120) qk[(size_t)row * 5120 + col] = val;
                    else            vT[(size_t)(col - 5120) * 2048 + row] = val;
                } else {
                    Cf[(size_t)row * 4096 + col] = nanfix(acc[i][j][r], 30000.0f);
                }
            }
        }
}

#undef SB
#undef SA
#undef LOADA4
#undef MFMAP4
#undef PHASE_SYNC
#undef PHASE_END

// ---------------- NeoX RoPE in-place on qk (stride 5120) ----------------------
// 256 threads = 4 heads per block; grid (2048, 10).
__global__ void rope_k(u16* __restrict__ qk, const int* __restrict__ positions) {
    const int s = blockIdx.x;
    const int h = blockIdx.y * 4 + (threadIdx.x >> 6);  // 0..39
    const int t = threadIdx.x & 63;                      // pair index
    u16* base = qk + (size_t)s * 5120 + ((h < 32) ? h * 128 : 4096 + (h - 32) * 128);
    const float pos = (float)positions[s];
    const float freq = pos * exp2f(-(float)t * (19.931568569324174f / 64.f));
    const float c = cosf(freq), sn = sinf(freq);
    const float x1 = bf2f(base[t]), x2 = bf2f(base[t + 64]);
    base[t]      = f2bf(x1 * c - x2 * sn);
    base[t + 64] = f2bf(x2 * c + x1 * sn);
}

// ---------------- flash attention, window=1024, sink, GQA 4:1 ------------------
// grid (q-tile 32, head 32), 256 threads = 4 waves; wave owns 16 q-rows.
// K staged async w/ XOR chunk swizzle; V from vT w/ stride-72 LDS; Q direct.
// Mid-tile barrier replaced by lgkmcnt(0): Ps is per-wave.
__global__ __launch_bounds__(256) void attn_k(
    const u16* __restrict__ qk, const u16* __restrict__ vT,
    const float* __restrict__ sink, u16* __restrict__ out)
{
    alignas(16) __shared__ u16 Ks[64 * 128];    // slot = row*16 + (chunk ^ (row&15))
    alignas(16) __shared__ u16 VsT[128 * 72];   // [vd][seq], stride 72 (144B = 9x16B)
    alignas(16) __shared__ u16 Ps[4][16 * 72];

    const int h = blockIdx.y, hk = h >> 2;
    const int q0 = blockIdx.x * 64;
    const int tid = threadIdx.x, wave = tid >> 6, lane = tid & 63;
    const int lr = lane & 15, qd = lane >> 4;
    const float scaling = 0.08838834764831845f;  // 1/sqrt(128)

    // Q fragments straight from global (post-RoPE)
    bf16x8 aq[4];
    #pragma unroll
    for (int kc = 0; kc < 4; kc++)
        aq[kc] = *(const bf16x8*)&qk[(size_t)(q0 + wave * 16 + lr) * 5120 + h * 128 + kc * 32 + qd * 8];

    const float sinkv = sink[h];
    float m_run[4], l_run[4];
    #pragma unroll
    for (int r = 0; r < 4; r++) { m_run[r] = sinkv; l_run[r] = 0.f; }
    f32x4 acc_o[8];
    #pragma unroll
    for (int i = 0; i < 8; i++) acc_o[i] = (f32x4){0.f, 0.f, 0.f, 0.f};

    const int jlo = (q0 - 1023) > 0 ? (q0 - 1023) : 0;
    const int t0 = jlo >> 6, t1 = q0 >> 6;

    for (int kt = t0; kt <= t1; kt++) {
        const int j0 = kt * 64;
        __syncthreads();  // WAR: prior-iter Ks/VsT reads complete
        // K tile: 64 rows x 128 u16 = 1024 chunks of 16B, async, XOR-swizzled
        #pragma unroll
        for (int p = 0; p < 4; p++) {
            const int idx = p * 256 + tid;
            const int r = idx >> 4, cs = idx & 15, c = cs ^ (r & 15);
            async16(&qk[(size_t)(j0 + r) * 5120 + 4096 + hk * 128 + c * 8],
                    Ks + (p * 256 + wave * 64) * 8);
        }
        // V tile from vT: 128 vd-rows x 64 seq
        #pragma unroll
        for (int p = 0; p < 4; p++) {
            const int idx = p * 256 + tid;
            const int vd = idx >> 3, sc2 = (idx & 7) * 8;
            const u16x8 v = *(const u16x8*)&vT[(size_t)(hk * 128 + vd) * 2048 + j0 + sc2];
            *(u16x8*)&VsT[vd * 72 + sc2] = v;
        }
        __syncthreads();  // RAW: K (vmcnt drained here) + V visible to all waves

        // S = Q K^T : per-wave 16x64
        float sv[4][4];
        #pragma unroll
        for (int nt = 0; nt < 4; nt++) {
            f32x4 s = (f32x4){0.f, 0.f, 0.f, 0.f};
            #pragma unroll
            for (int kc = 0; kc < 4; kc++) {
                const int krow = nt * 16 + lr;
                const bf16x8 bk = *(const bf16x8*)&Ks[(krow * 16 + ((kc * 4 + qd) ^ lr)) * 8];
                s = __builtin_amdgcn_mfma_f32_16x16x32_bf16(aq[kc], bk, s, 0, 0, 0);
            }
            #pragma unroll
            for (int r = 0; r < 4; r++) sv[nt][r] = s[r];
        }

        // mask + scale + rowmax (row = qd*4+r, col = nt*16+lr)
        float rmax[4] = {-1e30f, -1e30f, -1e30f, -1e30f};
        #pragma unroll
        for (int nt = 0; nt < 4; nt++) {
            const int kpos = j0 + nt * 16 + lr;
            #pragma unroll
            for (int r = 0; r < 4; r++) {
                const int qpos = q0 + wave * 16 + qd * 4 + r;
                const bool ok = (kpos <= qpos) && (qpos - kpos < 1024);
                const float x = ok ? sv[nt][r] * scaling : -1e30f;
                sv[nt][r] = x;
                rmax[r] = fmaxf(rmax[r], x);
            }
        }
        #pragma unroll
        for (int off = 1; off < 16; off <<= 1)
            #pragma unroll
            for (int r = 0; r < 4; r++)
                rmax[r] = fmaxf(rmax[r], __shfl_xor(rmax[r], off, 64));

        float alpha[4], rsum[4];
        #pragma unroll
        for (int r = 0; r < 4; r++) {
            const float mnew = fmaxf(m_run[r], rmax[r]);
            alpha[r] = __expf(m_run[r] - mnew);
            m_run[r] = mnew;
            rsum[r] = 0.f;
        }
        #pragma unroll
        for (int nt = 0; nt < 4; nt++)
            #pragma unroll
            for (int r = 0; r < 4; r++) {
                const float p = __expf(sv[nt][r] - m_run[r]);
                sv[nt][r] = p;
                rsum[r] += p;
            }
        #pragma unroll
        for (int off = 1; off < 16; off <<= 1)
            #pragma unroll
            for (int r = 0; r < 4; r++)
                rsum[r] += __shfl_xor(rsum[r], off, 64);
        #pragma unroll
        for (int r = 0; r < 4; r++)
            l_run[r] = l_run[r] * alpha[r] + rsum[r];

        // P (C-layout) -> LDS bridge (stride 72); per-wave buffer, so only
        // this wave's ds_writes need to drain before its own ds_reads.
        #pragma unroll
        for (int nt = 0; nt < 4; nt++)
            #pragma unroll
            for (int r = 0; r < 4; r++)
                Ps[wave][(qd * 4 + r) * 72 + nt * 16 + lr] = f2bf(sv[nt][r]);

        #pragma unroll
        for (int i = 0; i < 8; i++)
            #pragma unroll
            for (int r = 0; r < 4; r++) acc_o[i][r] *= alpha[r];

        asm volatile("s_waitcnt lgkmcnt(0)" ::: "memory");
        __builtin_amdgcn_sched_barrier(0);

        bf16x8 pa[2];
        #pragma unroll
        for (int kc = 0; kc < 2; kc++)
            pa[kc] = *(const bf16x8*)&Ps[wave][lr * 72 + kc * 32 + qd * 8];

        #pragma unroll
        for (int nt = 0; nt < 8; nt++)
            #pragma unroll
            for (int kc = 0; kc < 2; kc++) {
                const bf16x8 bv = *(const bf16x8*)&VsT[(nt * 16 + lr) * 72 + kc * 32 + qd * 8];
                acc_o[nt] = __builtin_amdgcn_mfma_f32_16x16x32_bf16(pa[kc], bv, acc_o[nt], 0, 0, 0);
            }
    }

    float invd[4];
    #pragma unroll
    for (int r = 0; r < 4; r++)
        invd[r] = 1.f / (l_run[r] + __expf(sinkv - m_run[r]));
    #pragma unroll
    for (int nt = 0; nt < 8; nt++) {
        const int col = h * 128 + nt * 16 + lr;
        #pragma unroll
        for (int r = 0; r < 4; r++) {
            const int row = q0 + wave * 16 + qd * 4 + r;
            out[(size_t)row * 4096 + col] = f2bf(nanfix(acc_o[nt][r] * invd[r], 8.0f));
        }
    }
}

extern "C" void kernel_launch(void* const* d_in, const int* in_sizes, int n_in,
                              void* d_out, int out_size, void* d_ws, size_t ws_size,
                              hipStream_t stream)
{
    (void)in_sizes; (void)n_in; (void)out_size; (void)ws_size;
    const float* hidden    = (const float*)d_in[0];
    const int*   positions = (const int*)d_in[1];
    const float* wq   = (const float*)d_in[2];
    const float* wk   = (const float*)d_in[3];
    const float* wv   = (const float*)d_in[4];
    const float* wo   = (const float*)d_in[5];
    const float* sink = (const float*)d_in[6];
    float* out = (float*)d_out;

    // Workspace (88 MB peak):
    //  [0,16M)   hiddenB (2048x4096 bf16)      -- dead after gemm_qkv
    //  [16,64M)  wqkvT (6144x4096 bf16)        -- dead after gemm_qkv
    //  [64,84M)  qk (2048x5120 bf16)
    //  [84,88M)  vT (1024x2048 bf16)
    //  reuse:    [0,32M) woT (4096x4096 bf16), [32,48M) attnB (2048x4096 bf16)
    char* ws = (char*)d_ws;
    u16* hiddenB = (u16*)(ws);
    u16* wqkvT   = (u16*)(ws + (size_t)16777216);
    u16* qk      = (u16*)(ws + (size_t)67108864);
    u16* vT      = (u16*)(ws + (size_t)88080384);
    u16* woT     = (u16*)(ws);
    u16* attnB   = (u16*)(ws + (size_t)33554432);

    // convert / transpose to bf16 (bandwidth passes)
    cvt_k <<<4096, 256, 0, stream>>>(hidden, hiddenB);
    cvtT_k<<<dim3(64, 64), 256, 0, stream>>>(wq, wqkvT, 4096, 4096);
    cvtT_k<<<dim3(16, 64), 256, 0, stream>>>(wk, wqkvT + (size_t)4096 * 4096, 4096, 1024);
    cvtT_k<<<dim3(16, 64), 256, 0, stream>>>(wv, wqkvT + (size_t)5120 * 4096, 4096, 1024);

    // fused QKV projection (q,k -> qk; v -> vT): 2048x6144, tiles 128x128,
    // grid 16x48 = 768 blocks, 2 blocks/CU co-resident
    gemm256<2, 0><<<768, 256, 0, stream>>>(hiddenB, wqkvT, qk, vT, nullptr);

    // wqkvT/hiddenB dead -> wo transpose into their space
    cvtT_k<<<dim3(64, 64), 256, 0, stream>>>(wo, woT, 4096, 4096);

    rope_k<<<dim3(2048, 10), 256, 0, stream>>>(qk, positions);
    attn_k<<<dim3(32, 32), 256, 0, stream>>>(qk, vT, sink, attnB);

    // out GEMM: 2048x4096, tiles 128x128, grid 16x32 = 512 blocks
    gemm256<2, 1><<<512, 256, 0, stream>>>(attnB, woT, nullptr, nullptr, out);
}